// Round 4
// baseline (12933.807 us; speedup 1.0000x reference)
//
#include <hip/hip_runtime.h>
#include <hip/hip_bf16.h>

#define SEQ 2048
#define DMODEL 768
#define NHEAD 8
#define DQK 128
#define DV 192
#define QKVN 1344   // 8*128 + 128 + 192
#define FFI 1536
#define NP 256
#define DP 128
#define DPI 256
#define NPR 65536   // 256*256

#define EPS_RMS 1.1920929e-07f
#define EPS_LN 1e-5f

__device__ inline float wave_sum(float v) {
#pragma unroll
  for (int o = 32; o > 0; o >>= 1) v += __shfl_xor(v, o, 64);
  return v;
}
__device__ inline float wave_max(float v) {
#pragma unroll
  for (int o = 32; o > 0; o >>= 1) v = fmaxf(v, __shfl_xor(v, o, 64));
  return v;
}

// rotary table. In f32, 10**linspace(1,8129,64) = [10, inf, inf, ...] so
// inv_freq = [0.1, 0, 0, ...]; only dims 0 and 64 rotate.
__global__ void pos_kernel(float* __restrict__ pos) {
  int i = blockIdx.x, l = threadIdx.x;  // l in 0..63
  float f = (l == 0) ? 0.1f * (float)i : 0.0f;
  pos[i * 128 + l] = f;
  pos[i * 128 + 64 + l] = f;
}

// per-row inverse RMS: sc[row] = rsqrt(mean(x^2) + eps)
__global__ void rowscale_kernel(const float* __restrict__ x, float* __restrict__ sc, int cols) {
  size_t row = blockIdx.x;
  int l = threadIdx.x;
  const float* xr = x + row * cols;
  float ss = 0.f;
  for (int c = l; c < cols; c += 64) { float v = xr[c]; ss += v * v; }
  ss = wave_sum(ss);
  if (l == 0) sc[row] = rsqrtf(ss / (float)cols + EPS_RMS);
}

// y = rmsnorm(x,w) + res   (res may alias y)
__global__ void rmsres_kernel(const float* __restrict__ x, const float* __restrict__ w,
                              const float* res, float* y, int cols) {
  size_t row = blockIdx.x;
  int l = threadIdx.x;
  const float* xr = x + row * cols;
  float ss = 0.f;
  for (int c = l; c < cols; c += 64) { float v = xr[c]; ss += v * v; }
  ss = wave_sum(ss);
  float r = rsqrtf(ss / (float)cols + EPS_RMS);
  float* yr = y + row * cols;
  const float* rr = res + row * cols;
  for (int c = l; c < cols; c += 64) yr[c] = xr[c] * r * w[c] + rr[c];
}

// q/k prep: LayerNorm(bias-free) + scale(q) + rotary. grid (SEQ, 9): y<8 -> q head y, y==8 -> k
__global__ void qk_prep_kernel(const float* __restrict__ qkv, const float* __restrict__ qw,
                               const float* __restrict__ kw, const float* __restrict__ pos,
                               float* __restrict__ q_r, float* __restrict__ k_t) {
  int i = blockIdx.x;
  int y = blockIdx.y;
  int l = threadIdx.x;
  int off = (y < 8) ? y * DQK : NHEAD * DQK;
  const float* row = qkv + (size_t)i * QKVN + off;
  float a = row[l], b = row[l + 64];
  float mu = wave_sum(a + b) * (1.0f / 128.0f);
  float da = a - mu, db = b - mu;
  float var = wave_sum(da * da + db * db) * (1.0f / 128.0f);
  float rs = rsqrtf(var + EPS_LN);
  const float* w = (y < 8) ? qw : kw;
  float na = da * rs * w[l], nb = db * rs * w[l + 64];
  if (y < 8) { na *= 0.125f; nb *= 0.125f; }  // SCALE = 64^-0.5
  float p0 = pos[i * 128 + l], p1 = pos[i * 128 + 64 + l];
  float ra = na * cosf(p0) - nb * sinf(p0);
  float rb = nb * cosf(p1) + na * sinf(p1);
  if (y < 8) {
    float* o = q_r + ((size_t)y * SEQ + i) * DQK;
    o[l] = ra; o[l + 64] = rb;
  } else {
    k_t[(size_t)l * SEQ + i] = ra;
    k_t[(size_t)(l + 64) * SEQ + i] = rb;
  }
}

// v prep: LayerNorm over 192 dims
__global__ void v_prep_kernel(const float* __restrict__ qkv, const float* __restrict__ vw,
                              float* __restrict__ v_n) {
  int i = blockIdx.x, l = threadIdx.x;
  const float* row = qkv + (size_t)i * QKVN + NHEAD * DQK + DQK;
  float x0 = row[l], x1 = row[l + 64], x2 = row[l + 128];
  float mu = wave_sum(x0 + x1 + x2) * (1.0f / 192.0f);
  float d0 = x0 - mu, d1 = x1 - mu, d2 = x2 - mu;
  float var = wave_sum(d0 * d0 + d1 * d1 + d2 * d2) * (1.0f / 192.0f);
  float rs = rsqrtf(var + EPS_LN);
  float* o = v_n + (size_t)i * DV;
  o[l] = d0 * rs * vw[l];
  o[l + 64] = d1 * rs * vw[l + 64];
  o[l + 128] = d2 * rs * vw[l + 128];
}

// attention: one block (256 thr) per (i, h). softclamp(sim+bias) -> softmax -> @v
__global__ __launch_bounds__(256) void attn_kernel(const float* __restrict__ q_r,
                                                   const float* __restrict__ k_t,
                                                   const float* __restrict__ v_n,
                                                   const float* __restrict__ pb,
                                                   float* __restrict__ ao) {
  __shared__ float qs[DQK];
  __shared__ float ps[SEQ];
  __shared__ float red[4];
  int i = blockIdx.x, h = blockIdx.y, tid = threadIdx.x;
  int wv = tid >> 6, ln = tid & 63;
  const float* q = q_r + ((size_t)h * SEQ + i) * DQK;
  if (tid < DQK) qs[tid] = q[tid];
  __syncthreads();
  float s[8];
#pragma unroll
  for (int b = 0; b < 8; b++) s[b] = 0.f;
  for (int d = 0; d < DQK; d++) {
    float qd = qs[d];
    const float* kr = k_t + (size_t)d * SEQ;
#pragma unroll
    for (int b = 0; b < 8; b++) s[b] += qd * kr[b * 256 + tid];
  }
  int ipb = i >> 3;
#pragma unroll
  for (int b = 0; b < 8; b++) {
    int j = b * 256 + tid;
    float bias = pb[((size_t)ipb * 256 + (j >> 3)) * 8 + h];
    s[b] = 5.0f * tanhf((s[b] + bias) * 0.2f);
  }
  float m = s[0];
#pragma unroll
  for (int b = 1; b < 8; b++) m = fmaxf(m, s[b]);
  m = wave_max(m);
  if (ln == 0) red[wv] = m;
  __syncthreads();
  m = fmaxf(fmaxf(red[0], red[1]), fmaxf(red[2], red[3]));
  float sum = 0.f;
#pragma unroll
  for (int b = 0; b < 8; b++) {
    float e = expf(s[b] - m);
    ps[b * 256 + tid] = e;
    sum += e;
  }
  sum = wave_sum(sum);
  __syncthreads();
  if (ln == 0) red[wv] = sum;
  __syncthreads();
  float inv = 1.0f / (red[0] + red[1] + red[2] + red[3]);
  for (int d = tid; d < DV; d += 256) {
    float acc = 0.f;
    for (int j = 0; j < SEQ; j += 4) {
      acc += ps[j] * v_n[(size_t)j * DV + d]
           + ps[j + 1] * v_n[(size_t)(j + 1) * DV + d]
           + ps[j + 2] * v_n[(size_t)(j + 2) * DV + d]
           + ps[j + 3] * v_n[(size_t)(j + 3) * DV + d];
    }
    ao[(size_t)i * (NHEAD * DV) + h * DV + d] = acc * inv;
  }
}

// pairwise attention over a 64-row n-chunk: one wave per (i, n_local); adds residual
__global__ void pw_attn_kernel(const float* __restrict__ pqk, const float* __restrict__ pv,
                               const float* __restrict__ resid, float* __restrict__ out,
                               int nbase) {
  int i = blockIdx.x, nl = blockIdx.y, l = threadIdx.x;
  __shared__ float qs[DP];
  __shared__ float ps[NP];
  const float* pq = pqk + ((size_t)nl * NP + i) * (2 * DP);
  qs[l] = pq[l];
  qs[l + 64] = pq[l + 64];
  __syncthreads();
  float s[4];
#pragma unroll
  for (int b = 0; b < 4; b++) {
    int j = b * 64 + l;
    const float* pk = pqk + ((size_t)nl * NP + j) * (2 * DP) + DP;
    float acc = 0.f;
#pragma unroll 8
    for (int d = 0; d < DP; d++) acc += qs[d] * pk[d];
    s[b] = acc;
  }
  float m = fmaxf(fmaxf(s[0], s[1]), fmaxf(s[2], s[3]));
  m = wave_max(m);
  float sum = 0.f;
#pragma unroll
  for (int b = 0; b < 4; b++) {
    float e = expf(s[b] - m);
    ps[b * 64 + l] = e;
    sum += e;
  }
  sum = wave_sum(sum);
  float inv = 1.0f / sum;
  __syncthreads();
  size_t gbase = (((size_t)(nbase + nl)) * NP + i) * DP;
#pragma unroll
  for (int half = 0; half < 2; half++) {
    int d = half * 64 + l;
    float acc = 0.f;
    for (int j = 0; j < NP; j++) acc += ps[j] * pv[((size_t)nl * NP + j) * DP + d];
    out[gbase + d] = acc * inv + resid[gbase + d];
  }
}

// fused pairwise FF: out = relu(rmsnorm(x,wp)@w1+b1)@w2 + b2 + x, one block per row
__global__ __launch_bounds__(256) void pw_ff_kernel(const float* __restrict__ X,
                                                    const float* __restrict__ wp,
                                                    const float* __restrict__ w1,
                                                    const float* __restrict__ b1,
                                                    const float* __restrict__ w2,
                                                    const float* __restrict__ b2,
                                                    float* __restrict__ out) {
  __shared__ float xr[DP];
  __shared__ float hs[DPI];
  __shared__ float red[4];
  size_t row = blockIdx.x;
  int tid = threadIdx.x, wv = tid >> 6, ln = tid & 63;
  const float* x = X + row * DP;
  float v = (tid < DP) ? x[tid] : 0.f;
  float ss = wave_sum(v * v);
  if (ln == 0) red[wv] = ss;
  __syncthreads();
  float rs = rsqrtf((red[0] + red[1] + red[2] + red[3]) * (1.0f / DP) + EPS_RMS);
  if (tid < DP) xr[tid] = v * rs * wp[tid];
  __syncthreads();
  float acc = b1[tid];
  for (int d = 0; d < DP; d++) acc += xr[d] * w1[d * DPI + tid];
  hs[tid] = fmaxf(acc, 0.f);
  __syncthreads();
  if (tid < DP) {
    float o = b2[tid];
    for (int t = 0; t < DPI; t++) o += hs[t] * w2[t * DP + tid];
    out[row * DP + tid] = o + x[tid];
  }
}

// generic f32 GEMM: C = A@B (+bias)(relu?)(+resid), optional fused A-side
// rmsnorm (ascale*aw) and exact GELU. K%16==0.
__global__ __launch_bounds__(256) void gemm_kernel(const float* __restrict__ A,
                                                   const float* __restrict__ B,
                                                   float* __restrict__ C, int M, int N, int K,
                                                   const float* __restrict__ bias,
                                                   const float* __restrict__ resid, int act,
                                                   const float* __restrict__ ascale,
                                                   const float* __restrict__ aw, int agelu) {
  __shared__ float As[16][68];
  __shared__ float Bs[16][68];
  int tid = threadIdx.x;
  int bm = blockIdx.y * 64, bn = blockIdx.x * 64;
  int tx = tid & 15, ty = tid >> 4;
  int ar = tid >> 4, ac = tid & 15;
  int br = tid >> 6, bc = tid & 63;
  float acc[4][4] = {};
  for (int k0 = 0; k0 < K; k0 += 16) {
#pragma unroll
    for (int u = 0; u < 4; u++) {
      int gm = bm + ar + u * 16;
      float av = 0.f;
      if (gm < M) {
        av = A[(size_t)gm * K + (k0 + ac)];
        if (ascale) av *= ascale[gm] * aw[k0 + ac];
        if (agelu) av = 0.5f * av * (1.0f + erff(av * 0.70710678118654752f));
      }
      As[ac][ar + u * 16] = av;
    }
#pragma unroll
    for (int u = 0; u < 4; u++) {
      int gn = bn + bc;
      Bs[br + u * 4][bc] = (gn < N) ? B[(size_t)(k0 + br + u * 4) * N + gn] : 0.0f;
    }
    __syncthreads();
#pragma unroll
    for (int kk = 0; kk < 16; kk++) {
      float4 av = *(const float4*)&As[kk][ty * 4];
      float4 bv = *(const float4*)&Bs[kk][tx * 4];
      float aa[4] = {av.x, av.y, av.z, av.w};
      float bb[4] = {bv.x, bv.y, bv.z, bv.w};
#pragma unroll
      for (int mi = 0; mi < 4; mi++)
#pragma unroll
        for (int ni = 0; ni < 4; ni++) acc[mi][ni] += aa[mi] * bb[ni];
    }
    __syncthreads();
  }
#pragma unroll
  for (int mi = 0; mi < 4; mi++) {
    int gm = bm + ty * 4 + mi;
    if (gm >= M) continue;
#pragma unroll
    for (int ni = 0; ni < 4; ni++) {
      int gn = bn + tx * 4 + ni;
      if (gn >= N) continue;
      float v = acc[mi][ni];
      if (bias) v += bias[gn];
      if (act) v = fmaxf(v, 0.0f);
      if (resid) v += resid[(size_t)gm * N + gn];
      C[(size_t)gm * N + gn] = v;
    }
  }
}

// final copy to f32 output: [single | pairwise]  (reference returns float32!)
__global__ void out_kernel(const float* __restrict__ S, const float* __restrict__ P,
                           float* __restrict__ out) {
  size_t idx = (size_t)blockIdx.x * 256 + threadIdx.x;
  const size_t n1 = (size_t)SEQ * DMODEL;
  const size_t n2 = (size_t)NPR * DP;
  if (idx < n1) out[idx] = S[idx];
  else if (idx < n1 + n2) out[idx] = P[idx - n1];
}

extern "C" void kernel_launch(void* const* d_in, const int* in_sizes, int n_in,
                              void* d_out, int out_size, void* d_ws, size_t ws_size,
                              hipStream_t stream) {
  const float* in_single   = (const float*)d_in[0];
  const float* in_pair     = (const float*)d_in[1];
  const float* attn_pre_w  = (const float*)d_in[2];
  const float* attn_post_w = (const float*)d_in[3];
  const float* qkv_w       = (const float*)d_in[4];
  const float* q_norm_w    = (const float*)d_in[5];
  const float* k_norm_w    = (const float*)d_in[6];
  const float* v_norm_w    = (const float*)d_in[7];
  const float* bias_rms_w  = (const float*)d_in[8];
  const float* bias_proj_w = (const float*)d_in[9];
  const float* out_w       = (const float*)d_in[10];
  const float* ff_pre_w    = (const float*)d_in[11];
  const float* ff_post_w   = (const float*)d_in[12];
  const float* ff_w1       = (const float*)d_in[13];
  const float* ff_b1       = (const float*)d_in[14];
  const float* ff_w2       = (const float*)d_in[15];
  const float* ff_b2       = (const float*)d_in[16];
  const float* pw_attn_pre = (const float*)d_in[17];
  const float* pw_qk_w     = (const float*)d_in[18];
  const float* pw_v_w      = (const float*)d_in[19];
  const float* pw_v_b      = (const float*)d_in[20];
  const float* pw_ff_pre   = (const float*)d_in[21];
  const float* pw_ff_w1    = (const float*)d_in[22];
  const float* pw_ff_b1    = (const float*)d_in[23];
  const float* pw_ff_w2    = (const float*)d_in[24];
  const float* pw_ff_b2    = (const float*)d_in[25];

  float* ws = (float*)d_ws;
  float* S    = ws;                  // 1,572,864
  float* Pc   = ws + 1572864;        // 8,388,608
  float* Pa   = ws + 9961472;        // 8,388,608
  float* pb   = ws + 18350080;       // 524,288
  float* pos  = ws + 18874368;       // 262,144
  float* scP  = ws + 19136512;       // 65,536
  float* scS  = ws + 19202048;       // 2,048
  float* TMP  = ws + 19204096;       // 8,650,752 (union)
  float* qkv  = TMP;                 // 2,752,512
  float* q_r  = TMP + 2752512;       // 2,097,152
  float* k_t  = TMP + 4849664;       // 262,144 (transposed)
  float* v_n  = TMP + 5111808;       // 393,216
  float* ao   = TMP + 5505024;       // 3,145,728
  float* t2   = TMP;                 // 1,572,864 (qkv dead)
  float* t1   = TMP + 2752512;       // 3,145,728
  float* pqkc = TMP;                 // 4,194,304 ([16384, 256])
  float* pvc  = TMP + 4194304;       // 2,097,152 ([16384, 128])

  hipMemcpyAsync(S, in_single, 1572864 * sizeof(float), hipMemcpyDeviceToDevice, stream);
  hipMemcpyAsync(Pc, in_pair, (size_t)8388608 * sizeof(float), hipMemcpyDeviceToDevice, stream);
  pos_kernel<<<SEQ, 64, 0, stream>>>(pos);

  for (int i = 0; i < 4; i++) {
    int j = i / 2;
    rowscale_kernel<<<NPR, 64, 0, stream>>>(Pc, scP, DP);
    rowscale_kernel<<<SEQ, 64, 0, stream>>>(S, scS, DMODEL);
    // pairwise bias: pb = gelu(rmsnorm(Pc)) @ proj  [65536, 8]
    gemm_kernel<<<dim3(1, 1024), 256, 0, stream>>>(Pc, bias_proj_w + (size_t)i * DP * 8, pb,
                                                   NPR, 8, DP, nullptr, nullptr, 0,
                                                   scP, bias_rms_w + i * DP, 1);
    // attention
    gemm_kernel<<<dim3(21, 32), 256, 0, stream>>>(S, qkv_w + (size_t)i * DMODEL * QKVN, qkv,
                                                  SEQ, QKVN, DMODEL, nullptr, nullptr, 0,
                                                  scS, attn_pre_w + i * DMODEL, 0);
    qk_prep_kernel<<<dim3(SEQ, 9), 64, 0, stream>>>(qkv, q_norm_w + i * DQK, k_norm_w + i * DQK,
                                                    pos, q_r, k_t);
    v_prep_kernel<<<SEQ, 64, 0, stream>>>(qkv, v_norm_w + i * DV, v_n);
    attn_kernel<<<dim3(SEQ, NHEAD), 256, 0, stream>>>(q_r, k_t, v_n, pb, ao);
    gemm_kernel<<<dim3(12, 32), 256, 0, stream>>>(ao, out_w + (size_t)i * (NHEAD * DV) * DMODEL,
                                                  t2, SEQ, DMODEL, NHEAD * DV, nullptr, nullptr, 0,
                                                  nullptr, nullptr, 0);
    rmsres_kernel<<<SEQ, 64, 0, stream>>>(t2, attn_post_w + i * DMODEL, S, S, DMODEL);
    // feedforward
    rowscale_kernel<<<SEQ, 64, 0, stream>>>(S, scS, DMODEL);
    gemm_kernel<<<dim3(24, 32), 256, 0, stream>>>(S, ff_w1 + (size_t)i * DMODEL * FFI, t1,
                                                  SEQ, FFI, DMODEL, ff_b1 + i * FFI, nullptr, 1,
                                                  scS, ff_pre_w + i * DMODEL, 0);
    gemm_kernel<<<dim3(12, 32), 256, 0, stream>>>(t1, ff_w2 + (size_t)i * FFI * DMODEL, t2,
                                                  SEQ, DMODEL, FFI, ff_b2 + i * DMODEL, nullptr, 0,
                                                  nullptr, nullptr, 0);
    rmsres_kernel<<<SEQ, 64, 0, stream>>>(t2, ff_post_w + i * DMODEL, S, S, DMODEL);
    // pairwise track (layers 0, 2), chunked over n in 4 x 64 rows
    if ((i & 1) == 0) {
      for (int c = 0; c < 4; c++) {
        const float* Ac = Pc + (size_t)c * 16384 * DP;
        const float* sc = scP + c * 16384;
        gemm_kernel<<<dim3(4, 256), 256, 0, stream>>>(Ac, pw_qk_w + (size_t)j * DP * 2 * DP, pqkc,
                                                      16384, 2 * DP, DP, nullptr, nullptr, 0,
                                                      sc, pw_attn_pre + j * DP, 0);
        gemm_kernel<<<dim3(2, 256), 256, 0, stream>>>(Ac, pw_v_w + (size_t)j * DP * DP, pvc,
                                                      16384, DP, DP, pw_v_b + j * DP, nullptr, 0,
                                                      sc, pw_attn_pre + j * DP, 0);
        pw_attn_kernel<<<dim3(NP, 64), 64, 0, stream>>>(pqkc, pvc, Pc, Pa, c * 64);
      }
      pw_ff_kernel<<<NPR, 256, 0, stream>>>(Pa, pw_ff_pre + j * DP,
                                            pw_ff_w1 + (size_t)j * DP * DPI, pw_ff_b1 + j * DPI,
                                            pw_ff_w2 + (size_t)j * DPI * DP, pw_ff_b2 + j * DP, Pc);
    }
  }
  size_t total = (size_t)SEQ * DMODEL + (size_t)NPR * DP;
  out_kernel<<<(total + 255) / 256, 256, 0, stream>>>(S, Pc, (float*)d_out);
}

// Round 5
// 9280.359 us; speedup vs baseline: 1.3937x; 1.3937x over previous
//
#include <hip/hip_runtime.h>
#include <hip/hip_bf16.h>

#define SEQ 2048
#define DMODEL 768
#define NHEAD 8
#define DQK 128
#define DV 192
#define QKVN 1344   // 8*128 + 128 + 192
#define FFI 1536
#define NP 256
#define DP 128
#define DPI 256
#define NPR 65536   // 256*256
#define QBLK 64
#define KB 32

#define EPS_RMS 1.1920929e-07f
#define EPS_LN 1e-5f

__device__ inline float wave_sum(float v) {
#pragma unroll
  for (int o = 32; o > 0; o >>= 1) v += __shfl_xor(v, o, 64);
  return v;
}
__device__ inline float wave_max(float v) {
#pragma unroll
  for (int o = 32; o > 0; o >>= 1) v = fmaxf(v, __shfl_xor(v, o, 64));
  return v;
}

// rotary table: in f32, 10**linspace(1,8129,64) = [10, inf, ...] -> only dim 0/64 rotate
__global__ void pos_kernel(float* __restrict__ pos) {
  int i = blockIdx.x, l = threadIdx.x;
  float f = (l == 0) ? 0.1f * (float)i : 0.0f;
  pos[i * 128 + l] = f;
  pos[i * 128 + 64 + l] = f;
}

__global__ void rowscale_kernel(const float* __restrict__ x, float* __restrict__ sc, int cols) {
  size_t row = blockIdx.x;
  int l = threadIdx.x;
  const float* xr = x + row * cols;
  float ss = 0.f;
  for (int c = l; c < cols; c += 64) { float v = xr[c]; ss += v * v; }
  ss = wave_sum(ss);
  if (l == 0) sc[row] = rsqrtf(ss / (float)cols + EPS_RMS);
}

// y = rmsnorm(x,w) + res (res may alias y)
__global__ void rmsres_kernel(const float* __restrict__ x, const float* __restrict__ w,
                              const float* res, float* y, int cols) {
  size_t row = blockIdx.x;
  int l = threadIdx.x;
  const float* xr = x + row * cols;
  float ss = 0.f;
  for (int c = l; c < cols; c += 64) { float v = xr[c]; ss += v * v; }
  ss = wave_sum(ss);
  float r = rsqrtf(ss / (float)cols + EPS_RMS);
  float* yr = y + row * cols;
  const float* rr = res + row * cols;
  for (int c = l; c < cols; c += 64) yr[c] = xr[c] * r * w[c] + rr[c];
}

// q/k prep: LayerNorm(bias-free) + scale(q) + rotary. grid (SEQ, 9): y<8 -> q head y, y==8 -> k
__global__ void qk_prep_kernel(const float* __restrict__ qkv, const float* __restrict__ qw,
                               const float* __restrict__ kw, const float* __restrict__ pos,
                               float* __restrict__ q_r, float* __restrict__ k_t) {
  int i = blockIdx.x;
  int y = blockIdx.y;
  int l = threadIdx.x;
  int off = (y < 8) ? y * DQK : NHEAD * DQK;
  const float* row = qkv + (size_t)i * QKVN + off;
  float a = row[l], b = row[l + 64];
  float mu = wave_sum(a + b) * (1.0f / 128.0f);
  float da = a - mu, db = b - mu;
  float var = wave_sum(da * da + db * db) * (1.0f / 128.0f);
  float rs = rsqrtf(var + EPS_LN);
  const float* w = (y < 8) ? qw : kw;
  float na = da * rs * w[l], nb = db * rs * w[l + 64];
  if (y < 8) { na *= 0.125f; nb *= 0.125f; }
  float p0 = pos[i * 128 + l], p1 = pos[i * 128 + 64 + l];
  float ra = na * cosf(p0) - nb * sinf(p0);
  float rb = nb * cosf(p1) + na * sinf(p1);
  if (y < 8) {
    float* o = q_r + ((size_t)y * SEQ + i) * DQK;
    o[l] = ra; o[l + 64] = rb;
  } else {
    k_t[(size_t)l * SEQ + i] = ra;
    k_t[(size_t)(l + 64) * SEQ + i] = rb;
  }
}

__global__ void v_prep_kernel(const float* __restrict__ qkv, const float* __restrict__ vw,
                              float* __restrict__ v_n) {
  int i = blockIdx.x, l = threadIdx.x;
  const float* row = qkv + (size_t)i * QKVN + NHEAD * DQK + DQK;
  float x0 = row[l], x1 = row[l + 64], x2 = row[l + 128];
  float mu = wave_sum(x0 + x1 + x2) * (1.0f / 192.0f);
  float d0 = x0 - mu, d1 = x1 - mu, d2 = x2 - mu;
  float var = wave_sum(d0 * d0 + d1 * d1 + d2 * d2) * (1.0f / 192.0f);
  float rs = rsqrtf(var + EPS_LN);
  float* o = v_n + (size_t)i * DV;
  o[l] = d0 * rs * vw[l];
  o[l + 64] = d1 * rs * vw[l + 64];
  o[l + 128] = d2 * rs * vw[l + 128];
}

// fused bias projection: pbt[h][row] = gelu(rmsnorm(P[row])) . proj[:,h]
__global__ __launch_bounds__(256) void pb_kernel(const float* __restrict__ P,
    const float* __restrict__ scP, const float* __restrict__ rmsw,
    const float* __restrict__ proj, float* __restrict__ pbt) {
  __shared__ float gs[32][130];
  __shared__ float projs[1024];
  int b = blockIdx.x, t = threadIdx.x;
  int row0 = b * 32;
  for (int f = t; f < 1024; f += 256) projs[f] = proj[f];
  for (int f = t; f < 32 * 128; f += 256) {
    int r = f >> 7, d = f & 127;
    float x = P[(size_t)(row0 + r) * DP + d] * scP[row0 + r] * rmsw[d];
    gs[r][d] = 0.5f * x * (1.0f + erff(x * 0.70710678118654752f));
  }
  __syncthreads();
  int hh = t >> 5, r = t & 31;
  float acc = 0.f;
#pragma unroll 4
  for (int d = 0; d < 128; d++) acc += gs[r][d] * projs[d * 8 + hh];
  pbt[(size_t)hh * NPR + row0 + r] = acc;
}

// flash attention: block = 64 q-rows x 1 head; K/V tiles (KB=32) staged in LDS.
__global__ __launch_bounds__(256) void attn_flash(const float* __restrict__ q_r,
    const float* __restrict__ k_t, const float* __restrict__ v_n,
    const float* __restrict__ pbt, float* __restrict__ ao) {
  __shared__ __align__(16) float Qs[128][66];  // [d][q]
  __shared__ __align__(16) float Ks[128][34];  // [d][k]
  __shared__ __align__(16) float Vs[KB][192];  // [k][dv]
  __shared__ __align__(16) float Ps[QBLK][34]; // [q][k]
  int ib = blockIdx.x, h = blockIdx.y, t = threadIdx.x;
  int i0 = ib * QBLK;
  // stage Q transposed
  for (int f = t; f < QBLK * 32; f += 256) {
    int qq = f >> 5, dq = f & 31;
    float4 v = *(const float4*)(q_r + ((size_t)h * SEQ + i0 + qq) * DQK + dq * 4);
    Qs[dq * 4 + 0][qq] = v.x; Qs[dq * 4 + 1][qq] = v.y;
    Qs[dq * 4 + 2][qq] = v.z; Qs[dq * 4 + 3][qq] = v.w;
  }
  int qg = t >> 4;   // 0..15
  int kg = t & 15;   // 0..15
  int qi0 = qg * 4;
  int kj0 = kg * 2;
  int dv0 = kg * 12;
  float m[4], l[4];
  float4 o[4][3];
#pragma unroll
  for (int r = 0; r < 4; r++) {
    m[r] = -1e30f; l[r] = 0.f;
#pragma unroll
    for (int s = 0; s < 3; s++) o[r][s] = make_float4(0.f, 0.f, 0.f, 0.f);
  }
  const float* pbb = pbt + (size_t)h * NPR + ((size_t)(ib * 8) + (qg >> 1)) * 256 + (kg >> 2);

  for (int k0 = 0; k0 < SEQ; k0 += KB) {
    // stage K tile (from transposed k_t: coalesced)
    for (int f = t; f < 128 * 8; f += 256) {
      int d = f >> 3, j4 = f & 7;
      float4 v = *(const float4*)(k_t + (size_t)d * SEQ + k0 + j4 * 4);
      Ks[d][j4 * 4 + 0] = v.x; Ks[d][j4 * 4 + 1] = v.y;
      Ks[d][j4 * 4 + 2] = v.z; Ks[d][j4 * 4 + 3] = v.w;
    }
    // stage V tile (flat copy, rows contiguous)
    {
      const float4* src = (const float4*)(v_n + (size_t)k0 * DV);
      float4* dst = (float4*)(&Vs[0][0]);
      for (int f = t; f < KB * 48; f += 256) dst[f] = src[f];
    }
    __syncthreads();
    // QK^T for this tile
    float s0[4] = {0.f, 0.f, 0.f, 0.f};
    float s1[4] = {0.f, 0.f, 0.f, 0.f};
#pragma unroll 4
    for (int d = 0; d < 128; d++) {
      float2 kv = *(const float2*)&Ks[d][kj0];
      float2 qa = *(const float2*)&Qs[d][qi0];
      float2 qb = *(const float2*)&Qs[d][qi0 + 2];
      s0[0] += qa.x * kv.x; s1[0] += qa.x * kv.y;
      s0[1] += qa.y * kv.x; s1[1] += qa.y * kv.y;
      s0[2] += qb.x * kv.x; s1[2] += qb.x * kv.y;
      s0[3] += qb.y * kv.x; s1[3] += qb.y * kv.y;
    }
    float bias = pbb[k0 >> 3];
#pragma unroll
    for (int r = 0; r < 4; r++) {
      float x0 = 0.4f * (s0[r] + bias);
      float e0 = __expf(fminf(x0, 60.f));
      s0[r] = 5.f * (e0 - 1.f) / (e0 + 1.f);
      float x1 = 0.4f * (s1[r] + bias);
      float e1 = __expf(fminf(x1, 60.f));
      s1[r] = 5.f * (e1 - 1.f) / (e1 + 1.f);
    }
    // online softmax update (per-row stats across the 16 kg lanes)
#pragma unroll
    for (int r = 0; r < 4; r++) {
      float mr = fmaxf(s0[r], s1[r]);
#pragma unroll
      for (int ofs = 1; ofs < 16; ofs <<= 1) mr = fmaxf(mr, __shfl_xor(mr, ofs, 64));
      float mn = fmaxf(m[r], mr);
      float p0 = __expf(s0[r] - mn);
      float p1 = __expf(s1[r] - mn);
      float ts = p0 + p1;
#pragma unroll
      for (int ofs = 1; ofs < 16; ofs <<= 1) ts += __shfl_xor(ts, ofs, 64);
      float scale = __expf(m[r] - mn);
      l[r] = l[r] * scale + ts;
      m[r] = mn;
      *(float2*)&Ps[qi0 + r][kj0] = make_float2(p0, p1);
#pragma unroll
      for (int s = 0; s < 3; s++) {
        o[r][s].x *= scale; o[r][s].y *= scale; o[r][s].z *= scale; o[r][s].w *= scale;
      }
    }
    __syncthreads();
    // PV accumulate
#pragma unroll 2
    for (int k = 0; k < KB; k++) {
      float4 v0 = *(const float4*)&Vs[k][dv0];
      float4 v1 = *(const float4*)&Vs[k][dv0 + 4];
      float4 v2 = *(const float4*)&Vs[k][dv0 + 8];
#pragma unroll
      for (int r = 0; r < 4; r++) {
        float p = Ps[qi0 + r][k];
        o[r][0].x += p * v0.x; o[r][0].y += p * v0.y; o[r][0].z += p * v0.z; o[r][0].w += p * v0.w;
        o[r][1].x += p * v1.x; o[r][1].y += p * v1.y; o[r][1].z += p * v1.z; o[r][1].w += p * v1.w;
        o[r][2].x += p * v2.x; o[r][2].y += p * v2.y; o[r][2].z += p * v2.z; o[r][2].w += p * v2.w;
      }
    }
    __syncthreads();
  }
#pragma unroll
  for (int r = 0; r < 4; r++) {
    float inv = 1.0f / l[r];
    float* orow = ao + (size_t)(i0 + qi0 + r) * (NHEAD * DV) + h * DV + dv0;
#pragma unroll
    for (int s = 0; s < 3; s++) {
      float4 w = o[r][s];
      w.x *= inv; w.y *= inv; w.z *= inv; w.w *= inv;
      *(float4*)(orow + s * 4) = w;
    }
  }
}

// pairwise attention over a 64-row n-chunk: one wave per (i, n_local); adds residual
__global__ void pw_attn_kernel(const float* __restrict__ pqk, const float* __restrict__ pv,
                               const float* __restrict__ resid, float* __restrict__ out,
                               int nbase) {
  int i = blockIdx.x, nl = blockIdx.y, l = threadIdx.x;
  __shared__ float qs[DP];
  __shared__ float ps[NP];
  const float* pq = pqk + ((size_t)nl * NP + i) * (2 * DP);
  qs[l] = pq[l];
  qs[l + 64] = pq[l + 64];
  __syncthreads();
  float s[4];
#pragma unroll
  for (int b = 0; b < 4; b++) {
    int j = b * 64 + l;
    const float* pk = pqk + ((size_t)nl * NP + j) * (2 * DP) + DP;
    float acc = 0.f;
#pragma unroll 8
    for (int d = 0; d < DP; d++) acc += qs[d] * pk[d];
    s[b] = acc;
  }
  float mm = fmaxf(fmaxf(s[0], s[1]), fmaxf(s[2], s[3]));
  mm = wave_max(mm);
  float sum = 0.f;
#pragma unroll
  for (int b = 0; b < 4; b++) {
    float e = expf(s[b] - mm);
    ps[b * 64 + l] = e;
    sum += e;
  }
  sum = wave_sum(sum);
  float inv = 1.0f / sum;
  __syncthreads();
  size_t gbase = (((size_t)(nbase + nl)) * NP + i) * DP;
#pragma unroll
  for (int half = 0; half < 2; half++) {
    int d = half * 64 + l;
    float acc = 0.f;
    for (int j = 0; j < NP; j++) acc += ps[j] * pv[((size_t)nl * NP + j) * DP + d];
    out[gbase + d] = acc * inv + resid[gbase + d];
  }
}

// fused pairwise FF, 8 rows per block: out = relu(rms(x)@w1+b1)@w2 + b2 + x
__global__ __launch_bounds__(256) void pw_ff_kernel(const float* __restrict__ X,
                                                    const float* __restrict__ wp,
                                                    const float* __restrict__ w1,
                                                    const float* __restrict__ b1,
                                                    const float* __restrict__ w2,
                                                    const float* __restrict__ b2,
                                                    float* __restrict__ out) {
  __shared__ __align__(16) float xs[8][128];
  __shared__ __align__(16) float hs[8][256];
  int b = blockIdx.x, t = threadIdx.x;
  size_t row0 = (size_t)b * 8;
  int r = t >> 5, l = t & 31;
  const float* xr = X + (row0 + r) * DP;
  float v[4];
  float ss = 0.f;
#pragma unroll
  for (int e = 0; e < 4; e++) { v[e] = xr[l + 32 * e]; ss += v[e] * v[e]; }
#pragma unroll
  for (int o = 16; o > 0; o >>= 1) ss += __shfl_xor(ss, o, 64);
  float rs = rsqrtf(ss * (1.0f / 128.0f) + EPS_RMS);
#pragma unroll
  for (int e = 0; e < 4; e++) xs[r][l + 32 * e] = v[e] * rs * wp[l + 32 * e];
  __syncthreads();
  // stage A: hs[rr][t] = relu(b1 + sum_d xs[rr][d]*w1[d][t])
  {
    float acc[8];
    float bb = b1[t];
#pragma unroll
    for (int rr = 0; rr < 8; rr++) acc[rr] = bb;
    for (int d = 0; d < 128; d += 4) {
      float w0 = w1[(size_t)(d + 0) * DPI + t];
      float w1v = w1[(size_t)(d + 1) * DPI + t];
      float w2v = w1[(size_t)(d + 2) * DPI + t];
      float w3 = w1[(size_t)(d + 3) * DPI + t];
#pragma unroll
      for (int rr = 0; rr < 8; rr++) {
        float4 xv = *(const float4*)&xs[rr][d];
        acc[rr] += xv.x * w0 + xv.y * w1v + xv.z * w2v + xv.w * w3;
      }
    }
#pragma unroll
    for (int rr = 0; rr < 8; rr++) hs[rr][t] = fmaxf(acc[rr], 0.f);
  }
  __syncthreads();
  // stage B: out[row][c] = b2 + sum_t hs[row][t]*w2[t][c] + x
  int c = t & 127, g = t >> 7;  // g=0 -> rows 0..3, g=1 -> rows 4..7
  float ob[4];
  float bb2 = b2[c];
#pragma unroll
  for (int rr = 0; rr < 4; rr++) ob[rr] = bb2;
  for (int tt = 0; tt < 256; tt += 4) {
    float w0 = w2[(size_t)(tt + 0) * DP + c];
    float w1v = w2[(size_t)(tt + 1) * DP + c];
    float w2v = w2[(size_t)(tt + 2) * DP + c];
    float w3 = w2[(size_t)(tt + 3) * DP + c];
#pragma unroll
    for (int rr = 0; rr < 4; rr++) {
      float4 hv = *(const float4*)&hs[g * 4 + rr][tt];
      ob[rr] += hv.x * w0 + hv.y * w1v + hv.z * w2v + hv.w * w3;
    }
  }
#pragma unroll
  for (int rr = 0; rr < 4; rr++) {
    size_t gi = (row0 + g * 4 + rr) * DP + c;
    out[gi] = ob[rr] + X[gi];
  }
}

// generic f32 GEMM: C = A@B (+bias)(relu?)(+resid), optional fused A-side rmsnorm + GELU
__global__ __launch_bounds__(256) void gemm_kernel(const float* __restrict__ A,
                                                   const float* __restrict__ B,
                                                   float* __restrict__ C, int M, int N, int K,
                                                   const float* __restrict__ bias,
                                                   const float* __restrict__ resid, int act,
                                                   const float* __restrict__ ascale,
                                                   const float* __restrict__ aw, int agelu) {
  __shared__ float As[16][68];
  __shared__ float Bs[16][68];
  int tid = threadIdx.x;
  int bm = blockIdx.y * 64, bn = blockIdx.x * 64;
  int tx = tid & 15, ty = tid >> 4;
  int ar = tid >> 4, ac = tid & 15;
  int br = tid >> 6, bc = tid & 63;
  float acc[4][4] = {};
  for (int k0 = 0; k0 < K; k0 += 16) {
#pragma unroll
    for (int u = 0; u < 4; u++) {
      int gm = bm + ar + u * 16;
      float av = 0.f;
      if (gm < M) {
        av = A[(size_t)gm * K + (k0 + ac)];
        if (ascale) av *= ascale[gm] * aw[k0 + ac];
        if (agelu) av = 0.5f * av * (1.0f + erff(av * 0.70710678118654752f));
      }
      As[ac][ar + u * 16] = av;
    }
#pragma unroll
    for (int u = 0; u < 4; u++) {
      int gn = bn + bc;
      Bs[br + u * 4][bc] = (gn < N) ? B[(size_t)(k0 + br + u * 4) * N + gn] : 0.0f;
    }
    __syncthreads();
#pragma unroll
    for (int kk = 0; kk < 16; kk++) {
      float4 av = *(const float4*)&As[kk][ty * 4];
      float4 bv = *(const float4*)&Bs[kk][tx * 4];
      float aa[4] = {av.x, av.y, av.z, av.w};
      float bb[4] = {bv.x, bv.y, bv.z, bv.w};
#pragma unroll
      for (int mi = 0; mi < 4; mi++)
#pragma unroll
        for (int ni = 0; ni < 4; ni++) acc[mi][ni] += aa[mi] * bb[ni];
    }
    __syncthreads();
  }
#pragma unroll
  for (int mi = 0; mi < 4; mi++) {
    int gm = bm + ty * 4 + mi;
    if (gm >= M) continue;
#pragma unroll
    for (int ni = 0; ni < 4; ni++) {
      int gn = bn + tx * 4 + ni;
      if (gn >= N) continue;
      float v = acc[mi][ni];
      if (bias) v += bias[gn];
      if (act) v = fmaxf(v, 0.0f);
      if (resid) v += resid[(size_t)gm * N + gn];
      C[(size_t)gm * N + gn] = v;
    }
  }
}

__global__ void out_kernel(const float* __restrict__ S, const float* __restrict__ P,
                           float* __restrict__ out) {
  size_t idx = (size_t)blockIdx.x * 256 + threadIdx.x;
  const size_t n1 = (size_t)SEQ * DMODEL;
  const size_t n2 = (size_t)NPR * DP;
  if (idx < n1) out[idx] = S[idx];
  else if (idx < n1 + n2) out[idx] = P[idx - n1];
}

extern "C" void kernel_launch(void* const* d_in, const int* in_sizes, int n_in,
                              void* d_out, int out_size, void* d_ws, size_t ws_size,
                              hipStream_t stream) {
  const float* in_single   = (const float*)d_in[0];
  const float* in_pair     = (const float*)d_in[1];
  const float* attn_pre_w  = (const float*)d_in[2];
  const float* attn_post_w = (const float*)d_in[3];
  const float* qkv_w       = (const float*)d_in[4];
  const float* q_norm_w    = (const float*)d_in[5];
  const float* k_norm_w    = (const float*)d_in[6];
  const float* v_norm_w    = (const float*)d_in[7];
  const float* bias_rms_w  = (const float*)d_in[8];
  const float* bias_proj_w = (const float*)d_in[9];
  const float* out_w       = (const float*)d_in[10];
  const float* ff_pre_w    = (const float*)d_in[11];
  const float* ff_post_w   = (const float*)d_in[12];
  const float* ff_w1       = (const float*)d_in[13];
  const float* ff_b1       = (const float*)d_in[14];
  const float* ff_w2       = (const float*)d_in[15];
  const float* ff_b2       = (const float*)d_in[16];
  const float* pw_attn_pre = (const float*)d_in[17];
  const float* pw_qk_w     = (const float*)d_in[18];
  const float* pw_v_w      = (const float*)d_in[19];
  const float* pw_v_b      = (const float*)d_in[20];
  const float* pw_ff_pre   = (const float*)d_in[21];
  const float* pw_ff_w1    = (const float*)d_in[22];
  const float* pw_ff_b1    = (const float*)d_in[23];
  const float* pw_ff_w2    = (const float*)d_in[24];
  const float* pw_ff_b2    = (const float*)d_in[25];

  float* ws = (float*)d_ws;
  float* S    = ws;                  // 1,572,864
  float* Pc   = ws + 1572864;        // 8,388,608
  float* Pa   = ws + 9961472;        // 8,388,608
  float* pbt  = ws + 18350080;       // 524,288  [h][row]
  float* pos  = ws + 18874368;       // 262,144
  float* scP  = ws + 19136512;       // 65,536
  float* scS  = ws + 19202048;       // 2,048
  float* TMP  = ws + 19204096;       // 8,650,752 (union)
  float* qkv  = TMP;                 // 2,752,512
  float* q_r  = TMP + 2752512;       // 2,097,152
  float* k_t  = TMP + 4849664;       // 262,144 (transposed [d][seq])
  float* v_n  = TMP + 5111808;       // 393,216
  float* ao   = TMP + 5505024;       // 3,145,728
  float* t2   = TMP;                 // 1,572,864 (qkv dead)
  float* t1   = TMP + 2752512;       // 3,145,728
  float* pqkc = TMP;                 // 4,194,304 ([16384, 256])
  float* pvc  = TMP + 4194304;       // 2,097,152 ([16384, 128])

  hipMemcpyAsync(S, in_single, 1572864 * sizeof(float), hipMemcpyDeviceToDevice, stream);
  hipMemcpyAsync(Pc, in_pair, (size_t)8388608 * sizeof(float), hipMemcpyDeviceToDevice, stream);
  pos_kernel<<<SEQ, 64, 0, stream>>>(pos);

  for (int i = 0; i < 4; i++) {
    int j = i / 2;
    rowscale_kernel<<<NPR, 64, 0, stream>>>(Pc, scP, DP);
    rowscale_kernel<<<SEQ, 64, 0, stream>>>(S, scS, DMODEL);
    // pairwise bias -> pbt[h][row]
    pb_kernel<<<2048, 256, 0, stream>>>(Pc, scP, bias_rms_w + i * DP,
                                        bias_proj_w + (size_t)i * DP * 8, pbt);
    // attention
    gemm_kernel<<<dim3(21, 32), 256, 0, stream>>>(S, qkv_w + (size_t)i * DMODEL * QKVN, qkv,
                                                  SEQ, QKVN, DMODEL, nullptr, nullptr, 0,
                                                  scS, attn_pre_w + i * DMODEL, 0);
    qk_prep_kernel<<<dim3(SEQ, 9), 64, 0, stream>>>(qkv, q_norm_w + i * DQK, k_norm_w + i * DQK,
                                                    pos, q_r, k_t);
    v_prep_kernel<<<SEQ, 64, 0, stream>>>(qkv, v_norm_w + i * DV, v_n);
    attn_flash<<<dim3(SEQ / QBLK, NHEAD), 256, 0, stream>>>(q_r, k_t, v_n, pbt, ao);
    gemm_kernel<<<dim3(12, 32), 256, 0, stream>>>(ao, out_w + (size_t)i * (NHEAD * DV) * DMODEL,
                                                  t2, SEQ, DMODEL, NHEAD * DV, nullptr, nullptr, 0,
                                                  nullptr, nullptr, 0);
    rmsres_kernel<<<SEQ, 64, 0, stream>>>(t2, attn_post_w + i * DMODEL, S, S, DMODEL);
    // feedforward
    rowscale_kernel<<<SEQ, 64, 0, stream>>>(S, scS, DMODEL);
    gemm_kernel<<<dim3(24, 32), 256, 0, stream>>>(S, ff_w1 + (size_t)i * DMODEL * FFI, t1,
                                                  SEQ, FFI, DMODEL, ff_b1 + i * FFI, nullptr, 1,
                                                  scS, ff_pre_w + i * DMODEL, 0);
    gemm_kernel<<<dim3(12, 32), 256, 0, stream>>>(t1, ff_w2 + (size_t)i * FFI * DMODEL, t2,
                                                  SEQ, DMODEL, FFI, ff_b2 + i * DMODEL, nullptr, 0,
                                                  nullptr, nullptr, 0);
    rmsres_kernel<<<SEQ, 64, 0, stream>>>(t2, ff_post_w + i * DMODEL, S, S, DMODEL);
    // pairwise track (layers 0, 2), chunked over n in 4 x 64 rows
    if ((i & 1) == 0) {
      for (int c = 0; c < 4; c++) {
        const float* Ac = Pc + (size_t)c * 16384 * DP;
        const float* sc = scP + c * 16384;
        gemm_kernel<<<dim3(4, 256), 256, 0, stream>>>(Ac, pw_qk_w + (size_t)j * DP * 2 * DP, pqkc,
                                                      16384, 2 * DP, DP, nullptr, nullptr, 0,
                                                      sc, pw_attn_pre + j * DP, 0);
        gemm_kernel<<<dim3(2, 256), 256, 0, stream>>>(Ac, pw_v_w + (size_t)j * DP * DP, pvc,
                                                      16384, DP, DP, pw_v_b + j * DP, nullptr, 0,
                                                      sc, pw_attn_pre + j * DP, 0);
        pw_attn_kernel<<<dim3(NP, 64), 64, 0, stream>>>(pqkc, pvc, Pc, Pa, c * 64);
      }
      pw_ff_kernel<<<NPR / 8, 256, 0, stream>>>(Pa, pw_ff_pre + j * DP,
                                                pw_ff_w1 + (size_t)j * DP * DPI, pw_ff_b1 + j * DPI,
                                                pw_ff_w2 + (size_t)j * DPI * DP, pw_ff_b2 + j * DP, Pc);
    }
  }
  size_t total = (size_t)SEQ * DMODEL + (size_t)NPR * DP;
  out_kernel<<<(total + 255) / 256, 256, 0, stream>>>(S, Pc, (float*)d_out);
}

// Round 6
// 8081.481 us; speedup vs baseline: 1.6004x; 1.1483x over previous
//
#include <hip/hip_runtime.h>
#include <hip/hip_bf16.h>

#define SEQ 2048
#define DMODEL 768
#define NHEAD 8
#define DQK 128
#define DV 192
#define QKVN 1344   // 8*128 + 128 + 192
#define FFI 1536
#define NP 256
#define DP 128
#define DPI 256
#define NPR 65536   // 256*256
#define QBLK 64
#define KB 32

#define EPS_RMS 1.1920929e-07f
#define EPS_LN 1e-5f

typedef __attribute__((ext_vector_type(8))) short bf16x8;
typedef __attribute__((ext_vector_type(4))) float f32x4;

__device__ inline float wave_sum(float v) {
#pragma unroll
  for (int o = 32; o > 0; o >>= 1) v += __shfl_xor(v, o, 64);
  return v;
}
__device__ inline float wave_max(float v) {
#pragma unroll
  for (int o = 32; o > 0; o >>= 1) v = fmaxf(v, __shfl_xor(v, o, 64));
  return v;
}
__device__ inline unsigned short f2bf(float x) {  // RNE f32 -> bf16 bits
  unsigned int u = __float_as_uint(x);
  u += 0x7fffu + ((u >> 16) & 1u);
  return (unsigned short)(u >> 16);
}

// rotary table: in f32, 10**linspace(1,8129,64) = [10, inf, ...] -> only dim 0/64 rotate
__global__ void pos_kernel(float* __restrict__ pos) {
  int i = blockIdx.x, l = threadIdx.x;
  float f = (l == 0) ? 0.1f * (float)i : 0.0f;
  pos[i * 128 + l] = f;
  pos[i * 128 + 64 + l] = f;
}

__global__ void rowscale_kernel(const float* __restrict__ x, float* __restrict__ sc, int cols) {
  size_t row = blockIdx.x;
  int l = threadIdx.x;
  const float* xr = x + row * cols;
  float ss = 0.f;
  for (int c = l; c < cols; c += 64) { float v = xr[c]; ss += v * v; }
  ss = wave_sum(ss);
  if (l == 0) sc[row] = rsqrtf(ss / (float)cols + EPS_RMS);
}

// y = rmsnorm(x,w) + res (res may alias y)
__global__ void rmsres_kernel(const float* __restrict__ x, const float* __restrict__ w,
                              const float* res, float* y, int cols) {
  size_t row = blockIdx.x;
  int l = threadIdx.x;
  const float* xr = x + row * cols;
  float ss = 0.f;
  for (int c = l; c < cols; c += 64) { float v = xr[c]; ss += v * v; }
  ss = wave_sum(ss);
  float r = rsqrtf(ss / (float)cols + EPS_RMS);
  float* yr = y + row * cols;
  const float* rr = res + row * cols;
  for (int c = l; c < cols; c += 64) yr[c] = xr[c] * r * w[c] + rr[c];
}

// weight transpose + f32->bf16: W[K][N] -> Wt[N][K] (K,N multiples of 32)
__global__ __launch_bounds__(256) void convT_kernel(const float* __restrict__ W,
                                                    unsigned short* __restrict__ Wt,
                                                    int K, int N) {
  __shared__ float ls[32][33];
  int n0 = blockIdx.x * 32, k0 = blockIdx.y * 32;
  int t = threadIdx.x;
  int c = t & 31, r4 = t >> 5;
#pragma unroll
  for (int p = 0; p < 4; p++) {
    int r = r4 + p * 8;
    ls[r][c] = W[(size_t)(k0 + r) * N + n0 + c];
  }
  __syncthreads();
#pragma unroll
  for (int p = 0; p < 4; p++) {
    int n = r4 + p * 8, k = t & 31;
    Wt[(size_t)(n0 + n) * K + k0 + k] = f2bf(ls[k][n]);
  }
}

// bf16 MFMA GEMM: C[M,N] = A[M,K](f32, opt fused rmsnorm scale) @ Bt[N][K](bf16)
// epilogue: +bias, relu, +resid. M%128==0, K%32==0; N arbitrary (guarded).
__global__ __launch_bounds__(256) void gemm_bf16(const float* __restrict__ A,
    const unsigned short* __restrict__ Bt, float* __restrict__ C,
    int M, int N, int K,
    const float* __restrict__ bias, const float* __restrict__ resid, int act,
    const float* __restrict__ ascale, const float* __restrict__ aw) {
  __shared__ unsigned short As[128 * 32];
  __shared__ unsigned short Bs[128 * 32];
  int t = threadIdx.x;
  int bm = blockIdx.y * 128, bn = blockIdx.x * 128;
  int w = t >> 6, l = t & 63;
  int wr = (w >> 1) * 64, wc = (w & 1) * 64;
  int lo = l & 15, kbyte = (l >> 4) * 16;
  f32x4 acc[4][4];
#pragma unroll
  for (int q = 0; q < 4; q++)
#pragma unroll
    for (int cb = 0; cb < 4; cb++) acc[q][cb] = (f32x4){0.f, 0.f, 0.f, 0.f};
  int arow = t >> 3, akq = (t & 7) * 4;
  int bnl = t >> 2, bkb = (t & 3) * 8;

  for (int k0 = 0; k0 < K; k0 += 32) {
    // stage A (f32 -> bf16, fused rmsnorm scale), swizzled [row][k]
#pragma unroll
    for (int p = 0; p < 4; p++) {
      int row = p * 32 + arow;
      float4 v = *(const float4*)(A + (size_t)(bm + row) * K + k0 + akq);
      if (ascale) {
        float s = ascale[bm + row];
        v.x *= s * aw[k0 + akq + 0]; v.y *= s * aw[k0 + akq + 1];
        v.z *= s * aw[k0 + akq + 2]; v.w *= s * aw[k0 + akq + 3];
      }
      unsigned int p0 = (unsigned int)f2bf(v.x) | ((unsigned int)f2bf(v.y) << 16);
      unsigned int p1 = (unsigned int)f2bf(v.z) | ((unsigned int)f2bf(v.w) << 16);
      int byte = (row * 64 + akq * 2) ^ ((row & 7) << 4);
      *(uint2*)(&As[byte >> 1]) = make_uint2(p0, p1);
    }
    // stage B (bf16 copy from Wt[N][K]), swizzled [n][k]
#pragma unroll
    for (int p = 0; p < 2; p++) {
      int n = p * 64 + bnl;
      bf16x8 bv = {0, 0, 0, 0, 0, 0, 0, 0};
      if (bn + n < N) bv = *(const bf16x8*)(Bt + (size_t)(bn + n) * K + k0 + bkb);
      int byte = (n * 64 + bkb * 2) ^ ((n & 7) << 4);
      *(bf16x8*)(&Bs[byte >> 1]) = bv;
    }
    __syncthreads();
    bf16x8 af[4], bfr[4];
#pragma unroll
    for (int q = 0; q < 4; q++) {
      int r = wr + q * 16 + lo;
      af[q] = *(const bf16x8*)(&As[((r * 64 + kbyte) ^ ((r & 7) << 4)) >> 1]);
      int n = wc + q * 16 + lo;
      bfr[q] = *(const bf16x8*)(&Bs[((n * 64 + kbyte) ^ ((n & 7) << 4)) >> 1]);
    }
#pragma unroll
    for (int q = 0; q < 4; q++)
#pragma unroll
      for (int cb = 0; cb < 4; cb++)
        acc[q][cb] = __builtin_amdgcn_mfma_f32_16x16x32_bf16(af[q], bfr[cb], acc[q][cb], 0, 0, 0);
    __syncthreads();
  }
#pragma unroll
  for (int q = 0; q < 4; q++) {
#pragma unroll
    for (int cb = 0; cb < 4; cb++) {
      int gn = bn + wc + cb * 16 + lo;
      if (gn >= N) continue;
#pragma unroll
      for (int i = 0; i < 4; i++) {
        int gm = bm + wr + q * 16 + (l >> 4) * 4 + i;
        float v = acc[q][cb][i];
        if (bias) v += bias[gn];
        if (act) v = fmaxf(v, 0.f);
        if (resid) v += resid[(size_t)gm * N + gn];
        C[(size_t)gm * N + gn] = v;
      }
    }
  }
}

// q/k prep: LayerNorm(bias-free) + scale(q) + rotary. grid (SEQ, 9): y<8 -> q head y, y==8 -> k
__global__ void qk_prep_kernel(const float* __restrict__ qkv, const float* __restrict__ qw,
                               const float* __restrict__ kw, const float* __restrict__ pos,
                               float* __restrict__ q_r, float* __restrict__ k_t) {
  int i = blockIdx.x;
  int y = blockIdx.y;
  int l = threadIdx.x;
  int off = (y < 8) ? y * DQK : NHEAD * DQK;
  const float* row = qkv + (size_t)i * QKVN + off;
  float a = row[l], b = row[l + 64];
  float mu = wave_sum(a + b) * (1.0f / 128.0f);
  float da = a - mu, db = b - mu;
  float var = wave_sum(da * da + db * db) * (1.0f / 128.0f);
  float rs = rsqrtf(var + EPS_LN);
  const float* w = (y < 8) ? qw : kw;
  float na = da * rs * w[l], nb = db * rs * w[l + 64];
  if (y < 8) { na *= 0.125f; nb *= 0.125f; }
  float p0 = pos[i * 128 + l], p1 = pos[i * 128 + 64 + l];
  float ra = na * cosf(p0) - nb * sinf(p0);
  float rb = nb * cosf(p1) + na * sinf(p1);
  if (y < 8) {
    float* o = q_r + ((size_t)y * SEQ + i) * DQK;
    o[l] = ra; o[l + 64] = rb;
  } else {
    k_t[(size_t)l * SEQ + i] = ra;
    k_t[(size_t)(l + 64) * SEQ + i] = rb;
  }
}

__global__ void v_prep_kernel(const float* __restrict__ qkv, const float* __restrict__ vw,
                              float* __restrict__ v_n) {
  int i = blockIdx.x, l = threadIdx.x;
  const float* row = qkv + (size_t)i * QKVN + NHEAD * DQK + DQK;
  float x0 = row[l], x1 = row[l + 64], x2 = row[l + 128];
  float mu = wave_sum(x0 + x1 + x2) * (1.0f / 192.0f);
  float d0 = x0 - mu, d1 = x1 - mu, d2 = x2 - mu;
  float var = wave_sum(d0 * d0 + d1 * d1 + d2 * d2) * (1.0f / 192.0f);
  float rs = rsqrtf(var + EPS_LN);
  float* o = v_n + (size_t)i * DV;
  o[l] = d0 * rs * vw[l];
  o[l + 64] = d1 * rs * vw[l + 64];
  o[l + 128] = d2 * rs * vw[l + 128];
}

// fused bias projection: pbt[h][row] = gelu(rmsnorm(P[row])) . proj[:,h]
__global__ __launch_bounds__(256) void pb_kernel(const float* __restrict__ P,
    const float* __restrict__ scP, const float* __restrict__ rmsw,
    const float* __restrict__ proj, float* __restrict__ pbt) {
  __shared__ float gs[32][130];
  __shared__ float projs[1024];
  int b = blockIdx.x, t = threadIdx.x;
  int row0 = b * 32;
  for (int f = t; f < 1024; f += 256) projs[f] = proj[f];
  for (int f = t; f < 32 * 128; f += 256) {
    int r = f >> 7, d = f & 127;
    float x = P[(size_t)(row0 + r) * DP + d] * scP[row0 + r] * rmsw[d];
    gs[r][d] = 0.5f * x * (1.0f + erff(x * 0.70710678118654752f));
  }
  __syncthreads();
  int hh = t >> 5, r = t & 31;
  float acc = 0.f;
#pragma unroll 4
  for (int d = 0; d < 128; d++) acc += gs[r][d] * projs[d * 8 + hh];
  pbt[(size_t)hh * NPR + row0 + r] = acc;
}

// flash attention: block = 64 q-rows x 1 head; K/V tiles (KB=32) staged in LDS.
__global__ __launch_bounds__(256) void attn_flash(const float* __restrict__ q_r,
    const float* __restrict__ k_t, const float* __restrict__ v_n,
    const float* __restrict__ pbt, float* __restrict__ ao) {
  __shared__ __align__(16) float Qs[128][66];
  __shared__ __align__(16) float Ks[128][34];
  __shared__ __align__(16) float Vs[KB][192];
  __shared__ __align__(16) float Ps[QBLK][34];
  int ib = blockIdx.x, h = blockIdx.y, t = threadIdx.x;
  int i0 = ib * QBLK;
  for (int f = t; f < QBLK * 32; f += 256) {
    int qq = f >> 5, dq = f & 31;
    float4 v = *(const float4*)(q_r + ((size_t)h * SEQ + i0 + qq) * DQK + dq * 4);
    Qs[dq * 4 + 0][qq] = v.x; Qs[dq * 4 + 1][qq] = v.y;
    Qs[dq * 4 + 2][qq] = v.z; Qs[dq * 4 + 3][qq] = v.w;
  }
  int qg = t >> 4;
  int kg = t & 15;
  int qi0 = qg * 4;
  int kj0 = kg * 2;
  int dv0 = kg * 12;
  float m[4], l[4];
  float4 o[4][3];
#pragma unroll
  for (int r = 0; r < 4; r++) {
    m[r] = -1e30f; l[r] = 0.f;
#pragma unroll
    for (int s = 0; s < 3; s++) o[r][s] = make_float4(0.f, 0.f, 0.f, 0.f);
  }
  const float* pbb = pbt + (size_t)h * NPR + ((size_t)(ib * 8) + (qg >> 1)) * 256 + (kg >> 2);

  for (int k0 = 0; k0 < SEQ; k0 += KB) {
    for (int f = t; f < 128 * 8; f += 256) {
      int d = f >> 3, j4 = f & 7;
      float4 v = *(const float4*)(k_t + (size_t)d * SEQ + k0 + j4 * 4);
      Ks[d][j4 * 4 + 0] = v.x; Ks[d][j4 * 4 + 1] = v.y;
      Ks[d][j4 * 4 + 2] = v.z; Ks[d][j4 * 4 + 3] = v.w;
    }
    {
      const float4* src = (const float4*)(v_n + (size_t)k0 * DV);
      float4* dst = (float4*)(&Vs[0][0]);
      for (int f = t; f < KB * 48; f += 256) dst[f] = src[f];
    }
    __syncthreads();
    float s0[4] = {0.f, 0.f, 0.f, 0.f};
    float s1[4] = {0.f, 0.f, 0.f, 0.f};
#pragma unroll 4
    for (int d = 0; d < 128; d++) {
      float2 kv = *(const float2*)&Ks[d][kj0];
      float2 qa = *(const float2*)&Qs[d][qi0];
      float2 qb = *(const float2*)&Qs[d][qi0 + 2];
      s0[0] += qa.x * kv.x; s1[0] += qa.x * kv.y;
      s0[1] += qa.y * kv.x; s1[1] += qa.y * kv.y;
      s0[2] += qb.x * kv.x; s1[2] += qb.x * kv.y;
      s0[3] += qb.y * kv.x; s1[3] += qb.y * kv.y;
    }
    float bias = pbb[k0 >> 3];
#pragma unroll
    for (int r = 0; r < 4; r++) {
      float x0 = 0.4f * (s0[r] + bias);
      float e0 = __expf(fminf(x0, 60.f));
      s0[r] = 5.f * (e0 - 1.f) / (e0 + 1.f);
      float x1 = 0.4f * (s1[r] + bias);
      float e1 = __expf(fminf(x1, 60.f));
      s1[r] = 5.f * (e1 - 1.f) / (e1 + 1.f);
    }
#pragma unroll
    for (int r = 0; r < 4; r++) {
      float mr = fmaxf(s0[r], s1[r]);
#pragma unroll
      for (int ofs = 1; ofs < 16; ofs <<= 1) mr = fmaxf(mr, __shfl_xor(mr, ofs, 64));
      float mn = fmaxf(m[r], mr);
      float p0 = __expf(s0[r] - mn);
      float p1 = __expf(s1[r] - mn);
      float ts = p0 + p1;
#pragma unroll
      for (int ofs = 1; ofs < 16; ofs <<= 1) ts += __shfl_xor(ts, ofs, 64);
      float scale = __expf(m[r] - mn);
      l[r] = l[r] * scale + ts;
      m[r] = mn;
      *(float2*)&Ps[qi0 + r][kj0] = make_float2(p0, p1);
#pragma unroll
      for (int s = 0; s < 3; s++) {
        o[r][s].x *= scale; o[r][s].y *= scale; o[r][s].z *= scale; o[r][s].w *= scale;
      }
    }
    __syncthreads();
#pragma unroll 2
    for (int k = 0; k < KB; k++) {
      float4 v0 = *(const float4*)&Vs[k][dv0];
      float4 v1 = *(const float4*)&Vs[k][dv0 + 4];
      float4 v2 = *(const float4*)&Vs[k][dv0 + 8];
#pragma unroll
      for (int r = 0; r < 4; r++) {
        float p = Ps[qi0 + r][k];
        o[r][0].x += p * v0.x; o[r][0].y += p * v0.y; o[r][0].z += p * v0.z; o[r][0].w += p * v0.w;
        o[r][1].x += p * v1.x; o[r][1].y += p * v1.y; o[r][1].z += p * v1.z; o[r][1].w += p * v1.w;
        o[r][2].x += p * v2.x; o[r][2].y += p * v2.y; o[r][2].z += p * v2.z; o[r][2].w += p * v2.w;
      }
    }
    __syncthreads();
  }
#pragma unroll
  for (int r = 0; r < 4; r++) {
    float inv = 1.0f / l[r];
    float* orow = ao + (size_t)(i0 + qi0 + r) * (NHEAD * DV) + h * DV + dv0;
#pragma unroll
    for (int s = 0; s < 3; s++) {
      float4 w = o[r][s];
      w.x *= inv; w.y *= inv; w.z *= inv; w.w *= inv;
      *(float4*)(orow + s * 4) = w;
    }
  }
}

// pairwise attention over a 64-row n-chunk: one wave per (i, n_local); adds residual
__global__ void pw_attn_kernel(const float* __restrict__ pqk, const float* __restrict__ pv,
                               const float* __restrict__ resid, float* __restrict__ out,
                               int nbase) {
  int i = blockIdx.x, nl = blockIdx.y, l = threadIdx.x;
  __shared__ float qs[DP];
  __shared__ float ps[NP];
  const float* pq = pqk + ((size_t)nl * NP + i) * (2 * DP);
  qs[l] = pq[l];
  qs[l + 64] = pq[l + 64];
  __syncthreads();
  float s[4];
#pragma unroll
  for (int b = 0; b < 4; b++) {
    int j = b * 64 + l;
    const float* pk = pqk + ((size_t)nl * NP + j) * (2 * DP) + DP;
    float acc = 0.f;
#pragma unroll 8
    for (int d = 0; d < DP; d++) acc += qs[d] * pk[d];
    s[b] = acc;
  }
  float mm = fmaxf(fmaxf(s[0], s[1]), fmaxf(s[2], s[3]));
  mm = wave_max(mm);
  float sum = 0.f;
#pragma unroll
  for (int b = 0; b < 4; b++) {
    float e = expf(s[b] - mm);
    ps[b * 64 + l] = e;
    sum += e;
  }
  sum = wave_sum(sum);
  float inv = 1.0f / sum;
  __syncthreads();
  size_t gbase = (((size_t)(nbase + nl)) * NP + i) * DP;
#pragma unroll
  for (int half = 0; half < 2; half++) {
    int d = half * 64 + l;
    float acc = 0.f;
    for (int j = 0; j < NP; j++) acc += ps[j] * pv[((size_t)nl * NP + j) * DP + d];
    out[gbase + d] = acc * inv + resid[gbase + d];
  }
}

// fused pairwise FF, 8 rows per block: out = relu(rms(x)@w1+b1)@w2 + b2 + x
__global__ __launch_bounds__(256) void pw_ff_kernel(const float* __restrict__ X,
                                                    const float* __restrict__ wp,
                                                    const float* __restrict__ w1,
                                                    const float* __restrict__ b1,
                                                    const float* __restrict__ w2,
                                                    const float* __restrict__ b2,
                                                    float* __restrict__ out) {
  __shared__ __align__(16) float xs[8][128];
  __shared__ __align__(16) float hs[8][256];
  int b = blockIdx.x, t = threadIdx.x;
  size_t row0 = (size_t)b * 8;
  int r = t >> 5, l = t & 31;
  const float* xr = X + (row0 + r) * DP;
  float v[4];
  float ss = 0.f;
#pragma unroll
  for (int e = 0; e < 4; e++) { v[e] = xr[l + 32 * e]; ss += v[e] * v[e]; }
#pragma unroll
  for (int o = 16; o > 0; o >>= 1) ss += __shfl_xor(ss, o, 64);
  float rs = rsqrtf(ss * (1.0f / 128.0f) + EPS_RMS);
#pragma unroll
  for (int e = 0; e < 4; e++) xs[r][l + 32 * e] = v[e] * rs * wp[l + 32 * e];
  __syncthreads();
  {
    float acc[8];
    float bb = b1[t];
#pragma unroll
    for (int rr = 0; rr < 8; rr++) acc[rr] = bb;
    for (int d = 0; d < 128; d += 4) {
      float w0 = w1[(size_t)(d + 0) * DPI + t];
      float w1v = w1[(size_t)(d + 1) * DPI + t];
      float w2v = w1[(size_t)(d + 2) * DPI + t];
      float w3 = w1[(size_t)(d + 3) * DPI + t];
#pragma unroll
      for (int rr = 0; rr < 8; rr++) {
        float4 xv = *(const float4*)&xs[rr][d];
        acc[rr] += xv.x * w0 + xv.y * w1v + xv.z * w2v + xv.w * w3;
      }
    }
#pragma unroll
    for (int rr = 0; rr < 8; rr++) hs[rr][t] = fmaxf(acc[rr], 0.f);
  }
  __syncthreads();
  int c = t & 127, g = t >> 7;
  float ob[4];
  float bb2 = b2[c];
#pragma unroll
  for (int rr = 0; rr < 4; rr++) ob[rr] = bb2;
  for (int tt = 0; tt < 256; tt += 4) {
    float w0 = w2[(size_t)(tt + 0) * DP + c];
    float w1v = w2[(size_t)(tt + 1) * DP + c];
    float w2v = w2[(size_t)(tt + 2) * DP + c];
    float w3 = w2[(size_t)(tt + 3) * DP + c];
#pragma unroll
    for (int rr = 0; rr < 4; rr++) {
      float4 hv = *(const float4*)&hs[g * 4 + rr][tt];
      ob[rr] += hv.x * w0 + hv.y * w1v + hv.z * w2v + hv.w * w3;
    }
  }
#pragma unroll
  for (int rr = 0; rr < 4; rr++) {
    size_t gi = (row0 + g * 4 + rr) * DP + c;
    out[gi] = ob[rr] + X[gi];
  }
}

__global__ void out_kernel(const float* __restrict__ S, const float* __restrict__ P,
                           float* __restrict__ out) {
  size_t idx = (size_t)blockIdx.x * 256 + threadIdx.x;
  const size_t n1 = (size_t)SEQ * DMODEL;
  const size_t n2 = (size_t)NPR * DP;
  if (idx < n1) out[idx] = S[idx];
  else if (idx < n1 + n2) out[idx] = P[idx - n1];
}

extern "C" void kernel_launch(void* const* d_in, const int* in_sizes, int n_in,
                              void* d_out, int out_size, void* d_ws, size_t ws_size,
                              hipStream_t stream) {
  const float* in_single   = (const float*)d_in[0];
  const float* in_pair     = (const float*)d_in[1];
  const float* attn_pre_w  = (const float*)d_in[2];
  const float* attn_post_w = (const float*)d_in[3];
  const float* qkv_w       = (const float*)d_in[4];
  const float* q_norm_w    = (const float*)d_in[5];
  const float* k_norm_w    = (const float*)d_in[6];
  const float* v_norm_w    = (const float*)d_in[7];
  const float* bias_rms_w  = (const float*)d_in[8];
  const float* bias_proj_w = (const float*)d_in[9];
  const float* out_w       = (const float*)d_in[10];
  const float* ff_pre_w    = (const float*)d_in[11];
  const float* ff_post_w   = (const float*)d_in[12];
  const float* ff_w1       = (const float*)d_in[13];
  const float* ff_b1       = (const float*)d_in[14];
  const float* ff_w2       = (const float*)d_in[15];
  const float* ff_b2       = (const float*)d_in[16];
  const float* pw_attn_pre = (const float*)d_in[17];
  const float* pw_qk_w     = (const float*)d_in[18];
  const float* pw_v_w      = (const float*)d_in[19];
  const float* pw_v_b      = (const float*)d_in[20];
  const float* pw_ff_pre   = (const float*)d_in[21];
  const float* pw_ff_w1    = (const float*)d_in[22];
  const float* pw_ff_b1    = (const float*)d_in[23];
  const float* pw_ff_w2    = (const float*)d_in[24];
  const float* pw_ff_b2    = (const float*)d_in[25];

  float* ws = (float*)d_ws;
  float* S    = ws;                  // 1,572,864
  float* Pc   = ws + 1572864;        // 8,388,608
  float* Pa   = ws + 9961472;        // 8,388,608
  float* pbt  = ws + 18350080;       // 524,288  [h][row]
  float* pos  = ws + 18874368;       // 262,144
  float* scP  = ws + 19136512;       // 65,536
  float* scS  = ws + 19202048;       // 2,048
  float* TMP  = ws + 19204096;       // 8,650,752 (union)
  // single-track overlays:
  float* qkv  = TMP;                 // 2,752,512
  float* q_r  = TMP + 2752512;       // 2,097,152
  float* k_t  = TMP + 4849664;       // 262,144 (transposed [d][seq])
  float* v_n  = TMP + 5111808;       // 393,216
  float* ao   = TMP + 5505024;       // 3,145,728
  unsigned short* WtA = (unsigned short*)(TMP + 5505024);  // qkv weights bf16 (pre-attn, ao dead)
  unsigned short* WtX = (unsigned short*)(TMP);            // out/ff weights bf16 (qkv dead)
  float* t2   = TMP + 655360;        // 1,572,864 (after WtX's 589,824 floats)
  float* t1   = TMP + 2752512;       // 3,145,728
  // pairwise overlays:
  float* pqkc = TMP;                 // 4,194,304 ([16384, 256])
  float* pvc  = TMP + 4194304;       // 2,097,152 ([16384, 128])
  unsigned short* WtE = (unsigned short*)(TMP + 6400000);  // pw_qk^T bf16 (32768)
  unsigned short* WtF = (unsigned short*)(TMP + 6420000);  // pw_v^T bf16 (16384)

  hipMemcpyAsync(S, in_single, 1572864 * sizeof(float), hipMemcpyDeviceToDevice, stream);
  hipMemcpyAsync(Pc, in_pair, (size_t)8388608 * sizeof(float), hipMemcpyDeviceToDevice, stream);
  pos_kernel<<<SEQ, 64, 0, stream>>>(pos);

  for (int i = 0; i < 4; i++) {
    int j = i / 2;
    rowscale_kernel<<<NPR, 64, 0, stream>>>(Pc, scP, DP);
    rowscale_kernel<<<SEQ, 64, 0, stream>>>(S, scS, DMODEL);
    pb_kernel<<<2048, 256, 0, stream>>>(Pc, scP, bias_rms_w + i * DP,
                                        bias_proj_w + (size_t)i * DP * 8, pbt);
    // qkv = rmsnorm(S) @ qkv_w   [bf16 MFMA]
    convT_kernel<<<dim3(QKVN / 32, DMODEL / 32), 256, 0, stream>>>(
        qkv_w + (size_t)i * DMODEL * QKVN, WtA, DMODEL, QKVN);
    gemm_bf16<<<dim3(11, 16), 256, 0, stream>>>(S, WtA, qkv, SEQ, QKVN, DMODEL,
                                                nullptr, nullptr, 0, scS, attn_pre_w + i * DMODEL);
    qk_prep_kernel<<<dim3(SEQ, 9), 64, 0, stream>>>(qkv, q_norm_w + i * DQK, k_norm_w + i * DQK,
                                                    pos, q_r, k_t);
    v_prep_kernel<<<SEQ, 64, 0, stream>>>(qkv, v_norm_w + i * DV, v_n);
    attn_flash<<<dim3(SEQ / QBLK, NHEAD), 256, 0, stream>>>(q_r, k_t, v_n, pbt, ao);
    // t2 = ao @ out_w
    convT_kernel<<<dim3(DMODEL / 32, (NHEAD * DV) / 32), 256, 0, stream>>>(
        out_w + (size_t)i * (NHEAD * DV) * DMODEL, WtX, NHEAD * DV, DMODEL);
    gemm_bf16<<<dim3(6, 16), 256, 0, stream>>>(ao, WtX, t2, SEQ, DMODEL, NHEAD * DV,
                                               nullptr, nullptr, 0, nullptr, nullptr);
    rmsres_kernel<<<SEQ, 64, 0, stream>>>(t2, attn_post_w + i * DMODEL, S, S, DMODEL);
    // feedforward
    rowscale_kernel<<<SEQ, 64, 0, stream>>>(S, scS, DMODEL);
    convT_kernel<<<dim3(FFI / 32, DMODEL / 32), 256, 0, stream>>>(
        ff_w1 + (size_t)i * DMODEL * FFI, WtX, DMODEL, FFI);
    gemm_bf16<<<dim3(12, 16), 256, 0, stream>>>(S, WtX, t1, SEQ, FFI, DMODEL,
                                                ff_b1 + i * FFI, nullptr, 1, scS, ff_pre_w + i * DMODEL);
    convT_kernel<<<dim3(DMODEL / 32, FFI / 32), 256, 0, stream>>>(
        ff_w2 + (size_t)i * FFI * DMODEL, WtX, FFI, DMODEL);
    gemm_bf16<<<dim3(6, 16), 256, 0, stream>>>(t1, WtX, t2, SEQ, DMODEL, FFI,
                                               ff_b2 + i * DMODEL, nullptr, 0, nullptr, nullptr);
    rmsres_kernel<<<SEQ, 64, 0, stream>>>(t2, ff_post_w + i * DMODEL, S, S, DMODEL);
    // pairwise track (layers 0, 2), chunked over n in 4 x 64 rows
    if ((i & 1) == 0) {
      convT_kernel<<<dim3((2 * DP) / 32, DP / 32), 256, 0, stream>>>(
          pw_qk_w + (size_t)j * DP * 2 * DP, WtE, DP, 2 * DP);
      convT_kernel<<<dim3(DP / 32, DP / 32), 256, 0, stream>>>(
          pw_v_w + (size_t)j * DP * DP, WtF, DP, DP);
      for (int c = 0; c < 4; c++) {
        const float* Ac = Pc + (size_t)c * 16384 * DP;
        const float* sc = scP + c * 16384;
        gemm_bf16<<<dim3(2, 128), 256, 0, stream>>>(Ac, WtE, pqkc, 16384, 2 * DP, DP,
                                                    nullptr, nullptr, 0, sc, pw_attn_pre + j * DP);
        gemm_bf16<<<dim3(1, 128), 256, 0, stream>>>(Ac, WtF, pvc, 16384, DP, DP,
                                                    pw_v_b + j * DP, nullptr, 0, sc, pw_attn_pre + j * DP);
        pw_attn_kernel<<<dim3(NP, 64), 64, 0, stream>>>(pqkc, pvc, Pc, Pa, c * 64);
      }
      pw_ff_kernel<<<NPR / 8, 256, 0, stream>>>(Pa, pw_ff_pre + j * DP,
                                                pw_ff_w1 + (size_t)j * DP * DPI, pw_ff_b1 + j * DPI,
                                                pw_ff_w2 + (size_t)j * DPI * DP, pw_ff_b2 + j * DP, Pc);
    }
  }
  size_t total = (size_t)SEQ * DMODEL + (size_t)NPR * DP;
  out_kernel<<<(total + 255) / 256, 256, 0, stream>>>(S, Pc, (float*)d_out);
}

// Round 7
// 6520.377 us; speedup vs baseline: 1.9836x; 1.2394x over previous
//
#include <hip/hip_runtime.h>
#include <hip/hip_bf16.h>

#define SEQ 2048
#define DMODEL 768
#define NHEAD 8
#define DQK 128
#define DV 192
#define QKVN 1344   // 8*128 + 128 + 192
#define FFI 1536
#define NP 256
#define DP 128
#define DPI 256
#define NPR 65536   // 256*256
#define KVB 64

#define EPS_RMS 1.1920929e-07f
#define EPS_LN 1e-5f

typedef __attribute__((ext_vector_type(8))) short bf16x8;
typedef __attribute__((ext_vector_type(4))) short bf16x4;
typedef __attribute__((ext_vector_type(4))) float f32x4;

__device__ inline float wave_sum(float v) {
#pragma unroll
  for (int o = 32; o > 0; o >>= 1) v += __shfl_xor(v, o, 64);
  return v;
}
__device__ inline float wave_max(float v) {
#pragma unroll
  for (int o = 32; o > 0; o >>= 1) v = fmaxf(v, __shfl_xor(v, o, 64));
  return v;
}
__device__ inline unsigned short f2bf(float x) {  // RNE f32 -> bf16 bits
  unsigned int u = __float_as_uint(x);
  u += 0x7fffu + ((u >> 16) & 1u);
  return (unsigned short)(u >> 16);
}
__device__ inline bf16x8 pack8(float4 a, float4 b) {
  bf16x8 r;
  r[0] = (short)f2bf(a.x); r[1] = (short)f2bf(a.y);
  r[2] = (short)f2bf(a.z); r[3] = (short)f2bf(a.w);
  r[4] = (short)f2bf(b.x); r[5] = (short)f2bf(b.y);
  r[6] = (short)f2bf(b.z); r[7] = (short)f2bf(b.w);
  return r;
}
__device__ inline bf16x4 pack4(float4 a) {
  bf16x4 r;
  r[0] = (short)f2bf(a.x); r[1] = (short)f2bf(a.y);
  r[2] = (short)f2bf(a.z); r[3] = (short)f2bf(a.w);
  return r;
}

// rotary table: in f32, 10**linspace(1,8129,64) = [10, inf, ...] -> only dim 0/64 rotate
__global__ void pos_kernel(float* __restrict__ pos) {
  int i = blockIdx.x, l = threadIdx.x;
  float f = (l == 0) ? 0.1f * (float)i : 0.0f;
  pos[i * 128 + l] = f;
  pos[i * 128 + 64 + l] = f;
}

__global__ void rowscale_kernel(const float* __restrict__ x, float* __restrict__ sc, int cols) {
  size_t row = blockIdx.x;
  int l = threadIdx.x;
  const float* xr = x + row * cols;
  float ss = 0.f;
  for (int c = l; c < cols; c += 64) { float v = xr[c]; ss += v * v; }
  ss = wave_sum(ss);
  if (l == 0) sc[row] = rsqrtf(ss / (float)cols + EPS_RMS);
}

// y = rmsnorm(x,w) + res (res may alias y)
__global__ void rmsres_kernel(const float* __restrict__ x, const float* __restrict__ w,
                              const float* res, float* y, int cols) {
  size_t row = blockIdx.x;
  int l = threadIdx.x;
  const float* xr = x + row * cols;
  float ss = 0.f;
  for (int c = l; c < cols; c += 64) { float v = xr[c]; ss += v * v; }
  ss = wave_sum(ss);
  float r = rsqrtf(ss / (float)cols + EPS_RMS);
  float* yr = y + row * cols;
  const float* rr = res + row * cols;
  for (int c = l; c < cols; c += 64) yr[c] = xr[c] * r * w[c] + rr[c];
}

// weight transpose + f32->bf16: W[K][N] -> Wt[N][K] (K,N multiples of 32)
__global__ __launch_bounds__(256) void convT_kernel(const float* __restrict__ W,
                                                    unsigned short* __restrict__ Wt,
                                                    int K, int N) {
  __shared__ float ls[32][33];
  int n0 = blockIdx.x * 32, k0 = blockIdx.y * 32;
  int t = threadIdx.x;
  int c = t & 31, r4 = t >> 5;
#pragma unroll
  for (int p = 0; p < 4; p++) {
    int r = r4 + p * 8;
    ls[r][c] = W[(size_t)(k0 + r) * N + n0 + c];
  }
  __syncthreads();
#pragma unroll
  for (int p = 0; p < 4; p++) {
    int n = r4 + p * 8, k = t & 31;
    Wt[(size_t)(n0 + n) * K + k0 + k] = f2bf(ls[k][n]);
  }
}

// bf16 MFMA GEMM: C[M,N] = A[M,K](f32, opt fused rmsnorm scale) @ Bt[N][K](bf16)
__global__ __launch_bounds__(256) void gemm_bf16(const float* __restrict__ A,
    const unsigned short* __restrict__ Bt, float* __restrict__ C,
    int M, int N, int K,
    const float* __restrict__ bias, const float* __restrict__ resid, int act,
    const float* __restrict__ ascale, const float* __restrict__ aw) {
  __shared__ unsigned short As[128 * 32];
  __shared__ unsigned short Bs[128 * 32];
  int t = threadIdx.x;
  int bm = blockIdx.y * 128, bn = blockIdx.x * 128;
  int w = t >> 6, l = t & 63;
  int wr = (w >> 1) * 64, wc = (w & 1) * 64;
  int lo = l & 15, kbyte = (l >> 4) * 16;
  f32x4 acc[4][4];
#pragma unroll
  for (int q = 0; q < 4; q++)
#pragma unroll
    for (int cb = 0; cb < 4; cb++) acc[q][cb] = (f32x4){0.f, 0.f, 0.f, 0.f};
  int arow = t >> 3, akq = (t & 7) * 4;
  int bnl = t >> 2, bkb = (t & 3) * 8;

  for (int k0 = 0; k0 < K; k0 += 32) {
#pragma unroll
    for (int p = 0; p < 4; p++) {
      int row = p * 32 + arow;
      float4 v = *(const float4*)(A + (size_t)(bm + row) * K + k0 + akq);
      if (ascale) {
        float s = ascale[bm + row];
        v.x *= s * aw[k0 + akq + 0]; v.y *= s * aw[k0 + akq + 1];
        v.z *= s * aw[k0 + akq + 2]; v.w *= s * aw[k0 + akq + 3];
      }
      unsigned int p0 = (unsigned int)f2bf(v.x) | ((unsigned int)f2bf(v.y) << 16);
      unsigned int p1 = (unsigned int)f2bf(v.z) | ((unsigned int)f2bf(v.w) << 16);
      int byte = (row * 64 + akq * 2) ^ ((row & 7) << 4);
      *(uint2*)(&As[byte >> 1]) = make_uint2(p0, p1);
    }
#pragma unroll
    for (int p = 0; p < 2; p++) {
      int n = p * 64 + bnl;
      bf16x8 bv = {0, 0, 0, 0, 0, 0, 0, 0};
      if (bn + n < N) bv = *(const bf16x8*)(Bt + (size_t)(bn + n) * K + k0 + bkb);
      int byte = (n * 64 + bkb * 2) ^ ((n & 7) << 4);
      *(bf16x8*)(&Bs[byte >> 1]) = bv;
    }
    __syncthreads();
    bf16x8 af[4], bfr[4];
#pragma unroll
    for (int q = 0; q < 4; q++) {
      int r = wr + q * 16 + lo;
      af[q] = *(const bf16x8*)(&As[((r * 64 + kbyte) ^ ((r & 7) << 4)) >> 1]);
      int n = wc + q * 16 + lo;
      bfr[q] = *(const bf16x8*)(&Bs[((n * 64 + kbyte) ^ ((n & 7) << 4)) >> 1]);
    }
#pragma unroll
    for (int q = 0; q < 4; q++)
#pragma unroll
      for (int cb = 0; cb < 4; cb++)
        acc[q][cb] = __builtin_amdgcn_mfma_f32_16x16x32_bf16(af[q], bfr[cb], acc[q][cb], 0, 0, 0);
    __syncthreads();
  }
#pragma unroll
  for (int q = 0; q < 4; q++) {
#pragma unroll
    for (int cb = 0; cb < 4; cb++) {
      int gn = bn + wc + cb * 16 + lo;
      if (gn >= N) continue;
#pragma unroll
      for (int i = 0; i < 4; i++) {
        int gm = bm + wr + q * 16 + (l >> 4) * 4 + i;
        float v = acc[q][cb][i];
        if (bias) v += bias[gn];
        if (act) v = fmaxf(v, 0.f);
        if (resid) v += resid[(size_t)gm * N + gn];
        C[(size_t)gm * N + gn] = v;
      }
    }
  }
}

// q/k prep: LayerNorm + scale(q) + rotary. K now written ROW-MAJOR k_n[seq][128].
__global__ void qk_prep_kernel(const float* __restrict__ qkv, const float* __restrict__ qw,
                               const float* __restrict__ kw, const float* __restrict__ pos,
                               float* __restrict__ q_r, float* __restrict__ k_n) {
  int i = blockIdx.x;
  int y = blockIdx.y;
  int l = threadIdx.x;
  int off = (y < 8) ? y * DQK : NHEAD * DQK;
  const float* row = qkv + (size_t)i * QKVN + off;
  float a = row[l], b = row[l + 64];
  float mu = wave_sum(a + b) * (1.0f / 128.0f);
  float da = a - mu, db = b - mu;
  float var = wave_sum(da * da + db * db) * (1.0f / 128.0f);
  float rs = rsqrtf(var + EPS_LN);
  const float* w = (y < 8) ? qw : kw;
  float na = da * rs * w[l], nb = db * rs * w[l + 64];
  if (y < 8) { na *= 0.125f; nb *= 0.125f; }
  float p0 = pos[i * 128 + l], p1 = pos[i * 128 + 64 + l];
  float ra = na * cosf(p0) - nb * sinf(p0);
  float rb = nb * cosf(p1) + na * sinf(p1);
  if (y < 8) {
    float* o = q_r + ((size_t)y * SEQ + i) * DQK;
    o[l] = ra; o[l + 64] = rb;
  } else {
    float* o = k_n + (size_t)i * DQK;
    o[l] = ra; o[l + 64] = rb;
  }
}

// v prep: LayerNorm over 192 dims; output TRANSPOSED v_t[dv][seq]
__global__ void v_prep_kernel(const float* __restrict__ qkv, const float* __restrict__ vw,
                              float* __restrict__ v_t) {
  int i = blockIdx.x, l = threadIdx.x;
  const float* row = qkv + (size_t)i * QKVN + NHEAD * DQK + DQK;
  float x0 = row[l], x1 = row[l + 64], x2 = row[l + 128];
  float mu = wave_sum(x0 + x1 + x2) * (1.0f / 192.0f);
  float d0 = x0 - mu, d1 = x1 - mu, d2 = x2 - mu;
  float var = wave_sum(d0 * d0 + d1 * d1 + d2 * d2) * (1.0f / 192.0f);
  float rs = rsqrtf(var + EPS_LN);
  v_t[(size_t)l * SEQ + i] = d0 * rs * vw[l];
  v_t[(size_t)(l + 64) * SEQ + i] = d1 * rs * vw[l + 64];
  v_t[(size_t)(l + 128) * SEQ + i] = d2 * rs * vw[l + 128];
}

// fused bias projection: pbt[h][row] = gelu(rmsnorm(P[row])) . proj[:,h]
__global__ __launch_bounds__(256) void pb_kernel(const float* __restrict__ P,
    const float* __restrict__ scP, const float* __restrict__ rmsw,
    const float* __restrict__ proj, float* __restrict__ pbt) {
  __shared__ float gs[32][130];
  __shared__ float projs[1024];
  int b = blockIdx.x, t = threadIdx.x;
  int row0 = b * 32;
  for (int f = t; f < 1024; f += 256) projs[f] = proj[f];
  for (int f = t; f < 32 * 128; f += 256) {
    int r = f >> 7, d = f & 127;
    float x = P[(size_t)(row0 + r) * DP + d] * scP[row0 + r] * rmsw[d];
    gs[r][d] = 0.5f * x * (1.0f + erff(x * 0.70710678118654752f));
  }
  __syncthreads();
  int hh = t >> 5, r = t & 31;
  float acc = 0.f;
#pragma unroll 4
  for (int d = 0; d < 128; d++) acc += gs[r][d] * projs[d * 8 + hh];
  pbt[(size_t)hh * NPR + row0 + r] = acc;
}

// ===== MFMA flash attention: 4 waves x 16 q-rows; KV tile = 64 keys =====
__global__ __launch_bounds__(256) void attn_mfma(const float* __restrict__ q_r,
    const float* __restrict__ k_n, const float* __restrict__ v_t,
    const float* __restrict__ pbt, float* __restrict__ ao) {
  __shared__ unsigned short Ks[64 * 128];   // [key][d]  bf16, swz
  __shared__ unsigned short Vs[192 * 64];   // [dv][key] bf16, swz
  __shared__ unsigned short Ps[4][16 * 64]; // per-wave [row][key] bf16, swz
  __shared__ float pb_lds[64];
  int ib = blockIdx.x, h = blockIdx.y, t = threadIdx.x;
  int i0 = ib * 64;
  int w = t >> 6, l = t & 63;
  int lo = l & 15, hi = l >> 4;

  // Q fragments (A-layout: row=lo, k = ks*32 + hi*8)
  bf16x8 qf[4];
  {
    const float* qp = q_r + ((size_t)h * SEQ + i0 + w * 16 + lo) * DQK + hi * 8;
#pragma unroll
    for (int ks = 0; ks < 4; ks++) {
      float4 a = *(const float4*)(qp + ks * 32);
      float4 b = *(const float4*)(qp + ks * 32 + 4);
      qf[ks] = pack8(a, b);
    }
  }
  float m_s[4], l_s[4];
  f32x4 o_acc[12];
#pragma unroll
  for (int i = 0; i < 4; i++) { m_s[i] = -1e30f; l_s[i] = 0.f; }
#pragma unroll
  for (int vc = 0; vc < 12; vc++) o_acc[vc] = (f32x4){0.f, 0.f, 0.f, 0.f};

  char* PsW = (char*)&Ps[w][0];

  for (int k0 = 0; k0 < SEQ; k0 += KVB) {
    // --- stage K tile [64][128] f32->bf16 swz ---
    {
      int row = t >> 2, d0 = (t & 3) * 32;
      const float* src = k_n + (size_t)(k0 + row) * DQK + d0;
#pragma unroll
      for (int jj = 0; jj < 4; jj++) {
        float4 a = *(const float4*)(src + jj * 8);
        float4 b = *(const float4*)(src + jj * 8 + 4);
        int byte = (row * 256 + (d0 + jj * 8) * 2) ^ ((row & 7) << 4);
        *(bf16x8*)((char*)Ks + byte) = pack8(a, b);
      }
    }
    // --- stage V tile [192 dv][64 keys] from v_t, f32->bf16 swz ---
#pragma unroll
    for (int f = t, rep = 0; rep < 12; f += 256, rep++) {
      int row = f >> 4, seg = f & 15;
      float4 a = *(const float4*)(v_t + (size_t)row * SEQ + k0 + seg * 4);
      int byte = (row * 128 + seg * 8) ^ ((row & 7) << 4);
      *(bf16x4*)((char*)Vs + byte) = pack4(a);
    }
    // --- stage bias tile (8 row-groups x 8 key-groups) ---
    if (t < 64) {
      int rg = t >> 3, kg = t & 7;
      pb_lds[t] = pbt[(size_t)h * NPR + ((i0 >> 3) + rg) * 256 + (k0 >> 3) + kg];
    }
    __syncthreads();
    // --- QK^T ---
    f32x4 sacc[4];
#pragma unroll
    for (int cs = 0; cs < 4; cs++) sacc[cs] = (f32x4){0.f, 0.f, 0.f, 0.f};
#pragma unroll
    for (int ks = 0; ks < 4; ks++) {
#pragma unroll
      for (int cs = 0; cs < 4; cs++) {
        int key = cs * 16 + lo;
        int byte = (key * 256 + (ks * 32 + hi * 8) * 2) ^ ((key & 7) << 4);
        bf16x8 bk = *(const bf16x8*)((char*)Ks + byte);
        sacc[cs] = __builtin_amdgcn_mfma_f32_16x16x32_bf16(qf[ks], bk, sacc[cs], 0, 0, 0);
      }
    }
    // --- bias + softclamp + online softmax ---
#pragma unroll
    for (int i = 0; i < 4; i++) {
      int rloc = w * 16 + hi * 4 + i;
      int rg = rloc >> 3;
      float sv[4];
      float mrow = -1e30f;
#pragma unroll
      for (int cs = 0; cs < 4; cs++) {
        int kg = cs * 2 + (lo >> 3);
        float x = 0.4f * (sacc[cs][i] + pb_lds[rg * 8 + kg]);
        float e = __expf(fminf(x, 60.f));
        sv[cs] = 5.f * (e - 1.f) / (e + 1.f);
        mrow = fmaxf(mrow, sv[cs]);
      }
#pragma unroll
      for (int ofs = 1; ofs < 16; ofs <<= 1) mrow = fmaxf(mrow, __shfl_xor(mrow, ofs, 64));
      float mn = fmaxf(m_s[i], mrow);
      float scale = __expf(m_s[i] - mn);
      float ts = 0.f;
      int r = hi * 4 + i;
#pragma unroll
      for (int cs = 0; cs < 4; cs++) {
        float p = __expf(sv[cs] - mn);
        ts += p;
        int key = cs * 16 + lo;
        int byte = (r * 128 + key * 2) ^ ((r & 7) << 4);
        *(unsigned short*)(PsW + byte) = f2bf(p);
      }
#pragma unroll
      for (int ofs = 1; ofs < 16; ofs <<= 1) ts += __shfl_xor(ts, ofs, 64);
      l_s[i] = l_s[i] * scale + ts;
      m_s[i] = mn;
#pragma unroll
      for (int vc = 0; vc < 12; vc++) o_acc[vc][i] *= scale;
    }
    // --- PV ---
#pragma unroll
    for (int ks2 = 0; ks2 < 2; ks2++) {
      int byte = (lo * 128 + (ks2 * 32 + hi * 8) * 2) ^ ((lo & 7) << 4);
      bf16x8 pa = *(const bf16x8*)(PsW + byte);
#pragma unroll
      for (int vc = 0; vc < 12; vc++) {
        int dv = vc * 16 + lo;
        int vbyte = (dv * 128 + (ks2 * 32 + hi * 8) * 2) ^ ((dv & 7) << 4);
        bf16x8 bv = *(const bf16x8*)((char*)Vs + vbyte);
        o_acc[vc] = __builtin_amdgcn_mfma_f32_16x16x32_bf16(pa, bv, o_acc[vc], 0, 0, 0);
      }
    }
    __syncthreads();
  }
  // --- epilogue ---
#pragma unroll
  for (int i = 0; i < 4; i++) {
    float inv = 1.0f / l_s[i];
    float* orow = ao + (size_t)(i0 + w * 16 + hi * 4 + i) * (NHEAD * DV) + h * DV;
#pragma unroll
    for (int vc = 0; vc < 12; vc++) orow[vc * 16 + lo] = o_acc[vc][i] * inv;
  }
}

// pairwise attention over a 64-row n-chunk: one wave per (i, n_local); adds residual
__global__ void pw_attn_kernel(const float* __restrict__ pqk, const float* __restrict__ pv,
                               const float* __restrict__ resid, float* __restrict__ out,
                               int nbase) {
  int i = blockIdx.x, nl = blockIdx.y, l = threadIdx.x;
  __shared__ float qs[DP];
  __shared__ float ps[NP];
  const float* pq = pqk + ((size_t)nl * NP + i) * (2 * DP);
  qs[l] = pq[l];
  qs[l + 64] = pq[l + 64];
  __syncthreads();
  float s[4];
#pragma unroll
  for (int b = 0; b < 4; b++) {
    int j = b * 64 + l;
    const float* pk = pqk + ((size_t)nl * NP + j) * (2 * DP) + DP;
    float acc = 0.f;
#pragma unroll 8
    for (int d = 0; d < DP; d++) acc += qs[d] * pk[d];
    s[b] = acc;
  }
  float mm = fmaxf(fmaxf(s[0], s[1]), fmaxf(s[2], s[3]));
  mm = wave_max(mm);
  float sum = 0.f;
#pragma unroll
  for (int b = 0; b < 4; b++) {
    float e = expf(s[b] - mm);
    ps[b * 64 + l] = e;
    sum += e;
  }
  sum = wave_sum(sum);
  float inv = 1.0f / sum;
  __syncthreads();
  size_t gbase = (((size_t)(nbase + nl)) * NP + i) * DP;
#pragma unroll
  for (int half = 0; half < 2; half++) {
    int d = half * 64 + l;
    float acc = 0.f;
    for (int j = 0; j < NP; j++) acc += ps[j] * pv[((size_t)nl * NP + j) * DP + d];
    out[gbase + d] = acc * inv + resid[gbase + d];
  }
}

// fused pairwise FF, 8 rows per block
__global__ __launch_bounds__(256) void pw_ff_kernel(const float* __restrict__ X,
                                                    const float* __restrict__ wp,
                                                    const float* __restrict__ w1,
                                                    const float* __restrict__ b1,
                                                    const float* __restrict__ w2,
                                                    const float* __restrict__ b2,
                                                    float* __restrict__ out) {
  __shared__ __align__(16) float xs[8][128];
  __shared__ __align__(16) float hs[8][256];
  int b = blockIdx.x, t = threadIdx.x;
  size_t row0 = (size_t)b * 8;
  int r = t >> 5, l = t & 31;
  const float* xr = X + (row0 + r) * DP;
  float v[4];
  float ss = 0.f;
#pragma unroll
  for (int e = 0; e < 4; e++) { v[e] = xr[l + 32 * e]; ss += v[e] * v[e]; }
#pragma unroll
  for (int o = 16; o > 0; o >>= 1) ss += __shfl_xor(ss, o, 64);
  float rs = rsqrtf(ss * (1.0f / 128.0f) + EPS_RMS);
#pragma unroll
  for (int e = 0; e < 4; e++) xs[r][l + 32 * e] = v[e] * rs * wp[l + 32 * e];
  __syncthreads();
  {
    float acc[8];
    float bb = b1[t];
#pragma unroll
    for (int rr = 0; rr < 8; rr++) acc[rr] = bb;
    for (int d = 0; d < 128; d += 4) {
      float w0 = w1[(size_t)(d + 0) * DPI + t];
      float w1v = w1[(size_t)(d + 1) * DPI + t];
      float w2v = w1[(size_t)(d + 2) * DPI + t];
      float w3 = w1[(size_t)(d + 3) * DPI + t];
#pragma unroll
      for (int rr = 0; rr < 8; rr++) {
        float4 xv = *(const float4*)&xs[rr][d];
        acc[rr] += xv.x * w0 + xv.y * w1v + xv.z * w2v + xv.w * w3;
      }
    }
#pragma unroll
    for (int rr = 0; rr < 8; rr++) hs[rr][t] = fmaxf(acc[rr], 0.f);
  }
  __syncthreads();
  int c = t & 127, g = t >> 7;
  float ob[4];
  float bb2 = b2[c];
#pragma unroll
  for (int rr = 0; rr < 4; rr++) ob[rr] = bb2;
  for (int tt = 0; tt < 256; tt += 4) {
    float w0 = w2[(size_t)(tt + 0) * DP + c];
    float w1v = w2[(size_t)(tt + 1) * DP + c];
    float w2v = w2[(size_t)(tt + 2) * DP + c];
    float w3 = w2[(size_t)(tt + 3) * DP + c];
#pragma unroll
    for (int rr = 0; rr < 4; rr++) {
      float4 hv = *(const float4*)&hs[g * 4 + rr][tt];
      ob[rr] += hv.x * w0 + hv.y * w1v + hv.z * w2v + hv.w * w3;
    }
  }
#pragma unroll
  for (int rr = 0; rr < 4; rr++) {
    size_t gi = (row0 + g * 4 + rr) * DP + c;
    out[gi] = ob[rr] + X[gi];
  }
}

__global__ void out_kernel(const float* __restrict__ S, const float* __restrict__ P,
                           float* __restrict__ out) {
  size_t idx = (size_t)blockIdx.x * 256 + threadIdx.x;
  const size_t n1 = (size_t)SEQ * DMODEL;
  const size_t n2 = (size_t)NPR * DP;
  if (idx < n1) out[idx] = S[idx];
  else if (idx < n1 + n2) out[idx] = P[idx - n1];
}

extern "C" void kernel_launch(void* const* d_in, const int* in_sizes, int n_in,
                              void* d_out, int out_size, void* d_ws, size_t ws_size,
                              hipStream_t stream) {
  const float* in_single   = (const float*)d_in[0];
  const float* in_pair     = (const float*)d_in[1];
  const float* attn_pre_w  = (const float*)d_in[2];
  const float* attn_post_w = (const float*)d_in[3];
  const float* qkv_w       = (const float*)d_in[4];
  const float* q_norm_w    = (const float*)d_in[5];
  const float* k_norm_w    = (const float*)d_in[6];
  const float* v_norm_w    = (const float*)d_in[7];
  const float* bias_rms_w  = (const float*)d_in[8];
  const float* bias_proj_w = (const float*)d_in[9];
  const float* out_w       = (const float*)d_in[10];
  const float* ff_pre_w    = (const float*)d_in[11];
  const float* ff_post_w   = (const float*)d_in[12];
  const float* ff_w1       = (const float*)d_in[13];
  const float* ff_b1       = (const float*)d_in[14];
  const float* ff_w2       = (const float*)d_in[15];
  const float* ff_b2       = (const float*)d_in[16];
  const float* pw_attn_pre = (const float*)d_in[17];
  const float* pw_qk_w     = (const float*)d_in[18];
  const float* pw_v_w      = (const float*)d_in[19];
  const float* pw_v_b      = (const float*)d_in[20];
  const float* pw_ff_pre   = (const float*)d_in[21];
  const float* pw_ff_w1    = (const float*)d_in[22];
  const float* pw_ff_b1    = (const float*)d_in[23];
  const float* pw_ff_w2    = (const float*)d_in[24];
  const float* pw_ff_b2    = (const float*)d_in[25];

  float* ws = (float*)d_ws;
  float* S    = ws;                  // 1,572,864
  float* Pc   = ws + 1572864;        // 8,388,608
  float* Pa   = ws + 9961472;        // 8,388,608
  float* pbt  = ws + 18350080;       // 524,288  [h][row]
  float* pos  = ws + 18874368;       // 262,144
  float* scP  = ws + 19136512;       // 65,536
  float* scS  = ws + 19202048;       // 2,048
  float* TMP  = ws + 19204096;       // 8,650,752 (union)
  // single-track overlays:
  float* qkv  = TMP;                 // 2,752,512
  float* q_r  = TMP + 2752512;       // 2,097,152
  float* k_n  = TMP + 4849664;       // 262,144 (row-major [seq][128])
  float* v_t  = TMP + 5111808;       // 393,216 (transposed [192][seq])
  float* ao   = TMP + 5505024;       // 3,145,728
  unsigned short* WtA = (unsigned short*)(TMP + 5505024);  // qkv weights bf16 (pre-attn, ao dead)
  unsigned short* WtX = (unsigned short*)(TMP);            // out/ff weights bf16 (qkv dead)
  float* t2   = TMP + 655360;        // 1,572,864
  float* t1   = TMP + 2752512;       // 3,145,728
  // pairwise overlays:
  float* pqkc = TMP;                 // 4,194,304 ([16384, 256])
  float* pvc  = TMP + 4194304;       // 2,097,152 ([16384, 128])
  unsigned short* WtE = (unsigned short*)(TMP + 6400000);  // pw_qk^T bf16
  unsigned short* WtF = (unsigned short*)(TMP + 6420000);  // pw_v^T bf16

  hipMemcpyAsync(S, in_single, 1572864 * sizeof(float), hipMemcpyDeviceToDevice, stream);
  hipMemcpyAsync(Pc, in_pair, (size_t)8388608 * sizeof(float), hipMemcpyDeviceToDevice, stream);
  pos_kernel<<<SEQ, 64, 0, stream>>>(pos);

  for (int i = 0; i < 4; i++) {
    int j = i / 2;
    rowscale_kernel<<<NPR, 64, 0, stream>>>(Pc, scP, DP);
    rowscale_kernel<<<SEQ, 64, 0, stream>>>(S, scS, DMODEL);
    pb_kernel<<<2048, 256, 0, stream>>>(Pc, scP, bias_rms_w + i * DP,
                                        bias_proj_w + (size_t)i * DP * 8, pbt);
    // qkv = rmsnorm(S) @ qkv_w   [bf16 MFMA]
    convT_kernel<<<dim3(QKVN / 32, DMODEL / 32), 256, 0, stream>>>(
        qkv_w + (size_t)i * DMODEL * QKVN, WtA, DMODEL, QKVN);
    gemm_bf16<<<dim3(11, 16), 256, 0, stream>>>(S, WtA, qkv, SEQ, QKVN, DMODEL,
                                                nullptr, nullptr, 0, scS, attn_pre_w + i * DMODEL);
    qk_prep_kernel<<<dim3(SEQ, 9), 64, 0, stream>>>(qkv, q_norm_w + i * DQK, k_norm_w + i * DQK,
                                                    pos, q_r, k_n);
    v_prep_kernel<<<SEQ, 64, 0, stream>>>(qkv, v_norm_w + i * DV, v_t);
    attn_mfma<<<dim3(SEQ / 64, NHEAD), 256, 0, stream>>>(q_r, k_n, v_t, pbt, ao);
    // t2 = ao @ out_w
    convT_kernel<<<dim3(DMODEL / 32, (NHEAD * DV) / 32), 256, 0, stream>>>(
        out_w + (size_t)i * (NHEAD * DV) * DMODEL, WtX, NHEAD * DV, DMODEL);
    gemm_bf16<<<dim3(6, 16), 256, 0, stream>>>(ao, WtX, t2, SEQ, DMODEL, NHEAD * DV,
                                               nullptr, nullptr, 0, nullptr, nullptr);
    rmsres_kernel<<<SEQ, 64, 0, stream>>>(t2, attn_post_w + i * DMODEL, S, S, DMODEL);
    // feedforward
    rowscale_kernel<<<SEQ, 64, 0, stream>>>(S, scS, DMODEL);
    convT_kernel<<<dim3(FFI / 32, DMODEL / 32), 256, 0, stream>>>(
        ff_w1 + (size_t)i * DMODEL * FFI, WtX, DMODEL, FFI);
    gemm_bf16<<<dim3(12, 16), 256, 0, stream>>>(S, WtX, t1, SEQ, FFI, DMODEL,
                                                ff_b1 + i * FFI, nullptr, 1, scS, ff_pre_w + i * DMODEL);
    convT_kernel<<<dim3(DMODEL / 32, FFI / 32), 256, 0, stream>>>(
        ff_w2 + (size_t)i * FFI * DMODEL, WtX, FFI, DMODEL);
    gemm_bf16<<<dim3(6, 16), 256, 0, stream>>>(t1, WtX, t2, SEQ, DMODEL, FFI,
                                               ff_b2 + i * DMODEL, nullptr, 0, nullptr, nullptr);
    rmsres_kernel<<<SEQ, 64, 0, stream>>>(t2, ff_post_w + i * DMODEL, S, S, DMODEL);
    // pairwise track (layers 0, 2), chunked over n in 4 x 64 rows
    if ((i & 1) == 0) {
      convT_kernel<<<dim3((2 * DP) / 32, DP / 32), 256, 0, stream>>>(
          pw_qk_w + (size_t)j * DP * 2 * DP, WtE, DP, 2 * DP);
      convT_kernel<<<dim3(DP / 32, DP / 32), 256, 0, stream>>>(
          pw_v_w + (size_t)j * DP * DP, WtF, DP, DP);
      for (int c = 0; c < 4; c++) {
        const float* Ac = Pc + (size_t)c * 16384 * DP;
        const float* sc = scP + c * 16384;
        gemm_bf16<<<dim3(2, 128), 256, 0, stream>>>(Ac, WtE, pqkc, 16384, 2 * DP, DP,
                                                    nullptr, nullptr, 0, sc, pw_attn_pre + j * DP);
        gemm_bf16<<<dim3(1, 128), 256, 0, stream>>>(Ac, WtF, pvc, 16384, DP, DP,
                                                    pw_v_b + j * DP, nullptr, 0, sc, pw_attn_pre + j * DP);
        pw_attn_kernel<<<dim3(NP, 64), 64, 0, stream>>>(pqkc, pvc, Pc, Pa, c * 64);
      }
      pw_ff_kernel<<<NPR / 8, 256, 0, stream>>>(Pa, pw_ff_pre + j * DP,
                                                pw_ff_w1 + (size_t)j * DP * DPI, pw_ff_b1 + j * DPI,
                                                pw_ff_w2 + (size_t)j * DPI * DP, pw_ff_b2 + j * DP, Pc);
    }
  }
  size_t total = (size_t)SEQ * DMODEL + (size_t)NPR * DP;
  out_kernel<<<(total + 255) / 256, 256, 0, stream>>>(S, Pc, (float*)d_out);
}

// Round 8
// 3403.175 us; speedup vs baseline: 3.8005x; 1.9160x over previous
//
#include <hip/hip_runtime.h>
#include <hip/hip_bf16.h>

#define SEQ 2048
#define DMODEL 768
#define NHEAD 8
#define DQK 128
#define DV 192
#define QKVN 1344   // 8*128 + 128 + 192
#define FFI 1536
#define NP 256
#define DP 128
#define DPI 256
#define NPR 65536   // 256*256
#define KVB 64

#define EPS_RMS 1.1920929e-07f
#define EPS_LN 1e-5f

typedef __attribute__((ext_vector_type(8))) short bf16x8;
typedef __attribute__((ext_vector_type(4))) short bf16x4;
typedef __attribute__((ext_vector_type(4))) float f32x4;

__device__ inline float wave_sum(float v) {
#pragma unroll
  for (int o = 32; o > 0; o >>= 1) v += __shfl_xor(v, o, 64);
  return v;
}
__device__ inline float wave_max(float v) {
#pragma unroll
  for (int o = 32; o > 0; o >>= 1) v = fmaxf(v, __shfl_xor(v, o, 64));
  return v;
}
__device__ inline unsigned short f2bf(float x) {  // RNE f32 -> bf16 bits
  unsigned int u = __float_as_uint(x);
  u += 0x7fffu + ((u >> 16) & 1u);
  return (unsigned short)(u >> 16);
}
__device__ inline bf16x8 pack8(float4 a, float4 b) {
  bf16x8 r;
  r[0] = (short)f2bf(a.x); r[1] = (short)f2bf(a.y);
  r[2] = (short)f2bf(a.z); r[3] = (short)f2bf(a.w);
  r[4] = (short)f2bf(b.x); r[5] = (short)f2bf(b.y);
  r[6] = (short)f2bf(b.z); r[7] = (short)f2bf(b.w);
  return r;
}
__device__ inline bf16x4 pack4(float4 a) {
  bf16x4 r;
  r[0] = (short)f2bf(a.x); r[1] = (short)f2bf(a.y);
  r[2] = (short)f2bf(a.z); r[3] = (short)f2bf(a.w);
  return r;
}

// rotary table: in f32, 10**linspace(1,8129,64) = [10, inf, ...] -> only dim 0/64 rotate
__global__ void pos_kernel(float* __restrict__ pos) {
  int i = blockIdx.x, l = threadIdx.x;
  float f = (l == 0) ? 0.1f * (float)i : 0.0f;
  pos[i * 128 + l] = f;
  pos[i * 128 + 64 + l] = f;
}

__global__ void rowscale_kernel(const float* __restrict__ x, float* __restrict__ sc, int cols) {
  size_t row = blockIdx.x;
  int l = threadIdx.x;
  const float* xr = x + row * cols;
  float ss = 0.f;
  for (int c = l; c < cols; c += 64) { float v = xr[c]; ss += v * v; }
  ss = wave_sum(ss);
  if (l == 0) sc[row] = rsqrtf(ss / (float)cols + EPS_RMS);
}

// y = rmsnorm(x,w) + res (res may alias y)
__global__ void rmsres_kernel(const float* __restrict__ x, const float* __restrict__ w,
                              const float* res, float* y, int cols) {
  size_t row = blockIdx.x;
  int l = threadIdx.x;
  const float* xr = x + row * cols;
  float ss = 0.f;
  for (int c = l; c < cols; c += 64) { float v = xr[c]; ss += v * v; }
  ss = wave_sum(ss);
  float r = rsqrtf(ss / (float)cols + EPS_RMS);
  float* yr = y + row * cols;
  const float* rr = res + row * cols;
  for (int c = l; c < cols; c += 64) yr[c] = xr[c] * r * w[c] + rr[c];
}

// weight transpose + f32->bf16: W[K][N] -> Wt[N][K] (K,N multiples of 32)
__global__ __launch_bounds__(256) void convT_kernel(const float* __restrict__ W,
                                                    unsigned short* __restrict__ Wt,
                                                    int K, int N) {
  __shared__ float ls[32][33];
  int n0 = blockIdx.x * 32, k0 = blockIdx.y * 32;
  int t = threadIdx.x;
  int c = t & 31, r4 = t >> 5;
#pragma unroll
  for (int p = 0; p < 4; p++) {
    int r = r4 + p * 8;
    ls[r][c] = W[(size_t)(k0 + r) * N + n0 + c];
  }
  __syncthreads();
#pragma unroll
  for (int p = 0; p < 4; p++) {
    int n = r4 + p * 8, k = t & 31;
    Wt[(size_t)(n0 + n) * K + k0 + k] = f2bf(ls[k][n]);
  }
}

// bf16 MFMA GEMM: C[M,N] = A[M,K](f32, opt fused rmsnorm scale) @ Bt[N][K](bf16)
__global__ __launch_bounds__(256) void gemm_bf16(const float* __restrict__ A,
    const unsigned short* __restrict__ Bt, float* __restrict__ C,
    int M, int N, int K,
    const float* __restrict__ bias, const float* __restrict__ resid, int act,
    const float* __restrict__ ascale, const float* __restrict__ aw) {
  __shared__ unsigned short As[128 * 32];
  __shared__ unsigned short Bs[128 * 32];
  int t = threadIdx.x;
  int bm = blockIdx.y * 128, bn = blockIdx.x * 128;
  int w = t >> 6, l = t & 63;
  int wr = (w >> 1) * 64, wc = (w & 1) * 64;
  int lo = l & 15, kbyte = (l >> 4) * 16;
  f32x4 acc[4][4];
#pragma unroll
  for (int q = 0; q < 4; q++)
#pragma unroll
    for (int cb = 0; cb < 4; cb++) acc[q][cb] = (f32x4){0.f, 0.f, 0.f, 0.f};
  int arow = t >> 3, akq = (t & 7) * 4;
  int bnl = t >> 2, bkb = (t & 3) * 8;

  for (int k0 = 0; k0 < K; k0 += 32) {
#pragma unroll
    for (int p = 0; p < 4; p++) {
      int row = p * 32 + arow;
      float4 v = *(const float4*)(A + (size_t)(bm + row) * K + k0 + akq);
      if (ascale) {
        float s = ascale[bm + row];
        v.x *= s * aw[k0 + akq + 0]; v.y *= s * aw[k0 + akq + 1];
        v.z *= s * aw[k0 + akq + 2]; v.w *= s * aw[k0 + akq + 3];
      }
      unsigned int p0 = (unsigned int)f2bf(v.x) | ((unsigned int)f2bf(v.y) << 16);
      unsigned int p1 = (unsigned int)f2bf(v.z) | ((unsigned int)f2bf(v.w) << 16);
      int byte = (row * 64 + akq * 2) ^ ((row & 7) << 4);
      *(uint2*)(&As[byte >> 1]) = make_uint2(p0, p1);
    }
#pragma unroll
    for (int p = 0; p < 2; p++) {
      int n = p * 64 + bnl;
      bf16x8 bv = {0, 0, 0, 0, 0, 0, 0, 0};
      if (bn + n < N) bv = *(const bf16x8*)(Bt + (size_t)(bn + n) * K + k0 + bkb);
      int byte = (n * 64 + bkb * 2) ^ ((n & 7) << 4);
      *(bf16x8*)(&Bs[byte >> 1]) = bv;
    }
    __syncthreads();
    bf16x8 af[4], bfr[4];
#pragma unroll
    for (int q = 0; q < 4; q++) {
      int r = wr + q * 16 + lo;
      af[q] = *(const bf16x8*)(&As[((r * 64 + kbyte) ^ ((r & 7) << 4)) >> 1]);
      int n = wc + q * 16 + lo;
      bfr[q] = *(const bf16x8*)(&Bs[((n * 64 + kbyte) ^ ((n & 7) << 4)) >> 1]);
    }
#pragma unroll
    for (int q = 0; q < 4; q++)
#pragma unroll
      for (int cb = 0; cb < 4; cb++)
        acc[q][cb] = __builtin_amdgcn_mfma_f32_16x16x32_bf16(af[q], bfr[cb], acc[q][cb], 0, 0, 0);
    __syncthreads();
  }
#pragma unroll
  for (int q = 0; q < 4; q++) {
#pragma unroll
    for (int cb = 0; cb < 4; cb++) {
      int gn = bn + wc + cb * 16 + lo;
      if (gn >= N) continue;
#pragma unroll
      for (int i = 0; i < 4; i++) {
        int gm = bm + wr + q * 16 + (l >> 4) * 4 + i;
        float v = acc[q][cb][i];
        if (bias) v += bias[gn];
        if (act) v = fmaxf(v, 0.f);
        if (resid) v += resid[(size_t)gm * N + gn];
        C[(size_t)gm * N + gn] = v;
      }
    }
  }
}

// q/k prep: LayerNorm + scale(q) + rotary. K written ROW-MAJOR k_n[seq][128].
__global__ void qk_prep_kernel(const float* __restrict__ qkv, const float* __restrict__ qw,
                               const float* __restrict__ kw, const float* __restrict__ pos,
                               float* __restrict__ q_r, float* __restrict__ k_n) {
  int i = blockIdx.x;
  int y = blockIdx.y;
  int l = threadIdx.x;
  int off = (y < 8) ? y * DQK : NHEAD * DQK;
  const float* row = qkv + (size_t)i * QKVN + off;
  float a = row[l], b = row[l + 64];
  float mu = wave_sum(a + b) * (1.0f / 128.0f);
  float da = a - mu, db = b - mu;
  float var = wave_sum(da * da + db * db) * (1.0f / 128.0f);
  float rs = rsqrtf(var + EPS_LN);
  const float* w = (y < 8) ? qw : kw;
  float na = da * rs * w[l], nb = db * rs * w[l + 64];
  if (y < 8) { na *= 0.125f; nb *= 0.125f; }
  float p0 = pos[i * 128 + l], p1 = pos[i * 128 + 64 + l];
  float ra = na * cosf(p0) - nb * sinf(p0);
  float rb = nb * cosf(p1) + na * sinf(p1);
  if (y < 8) {
    float* o = q_r + ((size_t)y * SEQ + i) * DQK;
    o[l] = ra; o[l + 64] = rb;
  } else {
    float* o = k_n + (size_t)i * DQK;
    o[l] = ra; o[l + 64] = rb;
  }
}

// v prep: LayerNorm over 192 dims; output TRANSPOSED v_t[dv][seq]
__global__ void v_prep_kernel(const float* __restrict__ qkv, const float* __restrict__ vw,
                              float* __restrict__ v_t) {
  int i = blockIdx.x, l = threadIdx.x;
  const float* row = qkv + (size_t)i * QKVN + NHEAD * DQK + DQK;
  float x0 = row[l], x1 = row[l + 64], x2 = row[l + 128];
  float mu = wave_sum(x0 + x1 + x2) * (1.0f / 192.0f);
  float d0 = x0 - mu, d1 = x1 - mu, d2 = x2 - mu;
  float var = wave_sum(d0 * d0 + d1 * d1 + d2 * d2) * (1.0f / 192.0f);
  float rs = rsqrtf(var + EPS_LN);
  v_t[(size_t)l * SEQ + i] = d0 * rs * vw[l];
  v_t[(size_t)(l + 64) * SEQ + i] = d1 * rs * vw[l + 64];
  v_t[(size_t)(l + 128) * SEQ + i] = d2 * rs * vw[l + 128];
}

// fused bias projection: pbt[h][row] = gelu(rmsnorm(P[row])) . proj[:,h]
__global__ __launch_bounds__(256) void pb_kernel(const float* __restrict__ P,
    const float* __restrict__ scP, const float* __restrict__ rmsw,
    const float* __restrict__ proj, float* __restrict__ pbt) {
  __shared__ float gs[32][130];
  __shared__ float projs[1024];
  int b = blockIdx.x, t = threadIdx.x;
  int row0 = b * 32;
  for (int f = t; f < 1024; f += 256) projs[f] = proj[f];
  for (int f = t; f < 32 * 128; f += 256) {
    int r = f >> 7, d = f & 127;
    float x = P[(size_t)(row0 + r) * DP + d] * scP[row0 + r] * rmsw[d];
    gs[r][d] = 0.5f * x * (1.0f + erff(x * 0.70710678118654752f));
  }
  __syncthreads();
  int hh = t >> 5, r = t & 31;
  float acc = 0.f;
#pragma unroll 4
  for (int d = 0; d < 128; d++) acc += gs[r][d] * projs[d * 8 + hh];
  pbt[(size_t)hh * NPR + row0 + r] = acc;
}

// ===== MFMA flash attention: 4 waves x 16 q-rows; KV tile = 64 keys =====
__global__ __launch_bounds__(256) void attn_mfma(const float* __restrict__ q_r,
    const float* __restrict__ k_n, const float* __restrict__ v_t,
    const float* __restrict__ pbt, float* __restrict__ ao) {
  __shared__ unsigned short Ks[64 * 128];   // [key][d]  bf16, swz
  __shared__ unsigned short Vs[192 * 64];   // [dv][key] bf16, swz
  __shared__ unsigned short Ps[4][16 * 64]; // per-wave [row][key] bf16, swz
  __shared__ float pb_lds[64];
  int ib = blockIdx.x, h = blockIdx.y, t = threadIdx.x;
  int i0 = ib * 64;
  int w = t >> 6, l = t & 63;
  int lo = l & 15, hi = l >> 4;

  bf16x8 qf[4];
  {
    const float* qp = q_r + ((size_t)h * SEQ + i0 + w * 16 + lo) * DQK + hi * 8;
#pragma unroll
    for (int ks = 0; ks < 4; ks++) {
      float4 a = *(const float4*)(qp + ks * 32);
      float4 b = *(const float4*)(qp + ks * 32 + 4);
      qf[ks] = pack8(a, b);
    }
  }
  float m_s[4], l_s[4];
  f32x4 o_acc[12];
#pragma unroll
  for (int i = 0; i < 4; i++) { m_s[i] = -1e30f; l_s[i] = 0.f; }
#pragma unroll
  for (int vc = 0; vc < 12; vc++) o_acc[vc] = (f32x4){0.f, 0.f, 0.f, 0.f};

  char* PsW = (char*)&Ps[w][0];

  for (int k0 = 0; k0 < SEQ; k0 += KVB) {
    {
      int row = t >> 2, d0 = (t & 3) * 32;
      const float* src = k_n + (size_t)(k0 + row) * DQK + d0;
#pragma unroll
      for (int jj = 0; jj < 4; jj++) {
        float4 a = *(const float4*)(src + jj * 8);
        float4 b = *(const float4*)(src + jj * 8 + 4);
        int byte = (row * 256 + (d0 + jj * 8) * 2) ^ ((row & 7) << 4);
        *(bf16x8*)((char*)Ks + byte) = pack8(a, b);
      }
    }
#pragma unroll
    for (int f = t, rep = 0; rep < 12; f += 256, rep++) {
      int row = f >> 4, seg = f & 15;
      float4 a = *(const float4*)(v_t + (size_t)row * SEQ + k0 + seg * 4);
      int byte = (row * 128 + seg * 8) ^ ((row & 7) << 4);
      *(bf16x4*)((char*)Vs + byte) = pack4(a);
    }
    if (t < 64) {
      int rg = t >> 3, kg = t & 7;
      pb_lds[t] = pbt[(size_t)h * NPR + ((i0 >> 3) + rg) * 256 + (k0 >> 3) + kg];
    }
    __syncthreads();
    f32x4 sacc[4];
#pragma unroll
    for (int cs = 0; cs < 4; cs++) sacc[cs] = (f32x4){0.f, 0.f, 0.f, 0.f};
#pragma unroll
    for (int ks = 0; ks < 4; ks++) {
#pragma unroll
      for (int cs = 0; cs < 4; cs++) {
        int key = cs * 16 + lo;
        int byte = (key * 256 + (ks * 32 + hi * 8) * 2) ^ ((key & 7) << 4);
        bf16x8 bk = *(const bf16x8*)((char*)Ks + byte);
        sacc[cs] = __builtin_amdgcn_mfma_f32_16x16x32_bf16(qf[ks], bk, sacc[cs], 0, 0, 0);
      }
    }
#pragma unroll
    for (int i = 0; i < 4; i++) {
      int rloc = w * 16 + hi * 4 + i;
      int rg = rloc >> 3;
      float sv[4];
      float mrow = -1e30f;
#pragma unroll
      for (int cs = 0; cs < 4; cs++) {
        int kg = cs * 2 + (lo >> 3);
        float x = 0.4f * (sacc[cs][i] + pb_lds[rg * 8 + kg]);
        float e = __expf(fminf(x, 60.f));
        sv[cs] = 5.f * (e - 1.f) / (e + 1.f);
        mrow = fmaxf(mrow, sv[cs]);
      }
#pragma unroll
      for (int ofs = 1; ofs < 16; ofs <<= 1) mrow = fmaxf(mrow, __shfl_xor(mrow, ofs, 64));
      float mn = fmaxf(m_s[i], mrow);
      float scale = __expf(m_s[i] - mn);
      float ts = 0.f;
      int r = hi * 4 + i;
#pragma unroll
      for (int cs = 0; cs < 4; cs++) {
        float p = __expf(sv[cs] - mn);
        ts += p;
        int key = cs * 16 + lo;
        int byte = (r * 128 + key * 2) ^ ((r & 7) << 4);
        *(unsigned short*)(PsW + byte) = f2bf(p);
      }
#pragma unroll
      for (int ofs = 1; ofs < 16; ofs <<= 1) ts += __shfl_xor(ts, ofs, 64);
      l_s[i] = l_s[i] * scale + ts;
      m_s[i] = mn;
#pragma unroll
      for (int vc = 0; vc < 12; vc++) o_acc[vc][i] *= scale;
    }
#pragma unroll
    for (int ks2 = 0; ks2 < 2; ks2++) {
      int byte = (lo * 128 + (ks2 * 32 + hi * 8) * 2) ^ ((lo & 7) << 4);
      bf16x8 pa = *(const bf16x8*)(PsW + byte);
#pragma unroll
      for (int vc = 0; vc < 12; vc++) {
        int dv = vc * 16 + lo;
        int vbyte = (dv * 128 + (ks2 * 32 + hi * 8) * 2) ^ ((dv & 7) << 4);
        bf16x8 bv = *(const bf16x8*)((char*)Vs + vbyte);
        o_acc[vc] = __builtin_amdgcn_mfma_f32_16x16x32_bf16(pa, bv, o_acc[vc], 0, 0, 0);
      }
    }
    __syncthreads();
  }
#pragma unroll
  for (int i = 0; i < 4; i++) {
    float inv = 1.0f / l_s[i];
    float* orow = ao + (size_t)(i0 + w * 16 + hi * 4 + i) * (NHEAD * DV) + h * DV;
#pragma unroll
    for (int vc = 0; vc < 12; vc++) orow[vc * 16 + lo] = o_acc[vc][i] * inv;
  }
}

// ===== MFMA pairwise attention: block = (64 q-rows) x (n-slice); +residual =====
__global__ __launch_bounds__(256) void pw_attn_mfma(const float* __restrict__ pqk,
    const float* __restrict__ pv, const float* __restrict__ resid,
    float* __restrict__ out, int nbase) {
  __shared__ unsigned short Ks[64 * 128];   // [key][d]  bf16, swz
  __shared__ unsigned short Vs[128 * 64];   // [dv][key] bf16, swz
  __shared__ unsigned short Ps[4][16 * 64]; // per-wave [row][key] bf16, swz
  int qb = blockIdx.x, nl = blockIdx.y, t = threadIdx.x;
  int i0 = qb * 64;
  int w = t >> 6, l = t & 63;
  int lo = l & 15, hi = l >> 4;
  size_t nrow = (size_t)nl * NP;  // row base within this chunk

  // Q fragments (A-layout: row=lo, k = ks*32 + hi*8)
  bf16x8 qf[4];
  {
    const float* qp = pqk + (nrow + i0 + w * 16 + lo) * (2 * DP) + hi * 8;
#pragma unroll
    for (int ks = 0; ks < 4; ks++) {
      float4 a = *(const float4*)(qp + ks * 32);
      float4 b = *(const float4*)(qp + ks * 32 + 4);
      qf[ks] = pack8(a, b);
    }
  }
  float m_s[4], l_s[4];
  f32x4 o_acc[8];
#pragma unroll
  for (int i = 0; i < 4; i++) { m_s[i] = -1e30f; l_s[i] = 0.f; }
#pragma unroll
  for (int vc = 0; vc < 8; vc++) o_acc[vc] = (f32x4){0.f, 0.f, 0.f, 0.f};
  char* PsW = (char*)&Ps[w][0];

  for (int k0 = 0; k0 < NP; k0 += 64) {
    // stage K tile [64][128] from pqk second half
    {
      int row = t >> 2, d0 = (t & 3) * 32;
      const float* src = pqk + (nrow + k0 + row) * (2 * DP) + DP + d0;
#pragma unroll
      for (int jj = 0; jj < 4; jj++) {
        float4 a = *(const float4*)(src + jj * 8);
        float4 b = *(const float4*)(src + jj * 8 + 4);
        int byte = (row * 256 + (d0 + jj * 8) * 2) ^ ((row & 7) << 4);
        *(bf16x8*)((char*)Ks + byte) = pack8(a, b);
      }
    }
    // stage V tile transposed [128 dv][64 keys] from row-major pv
    {
      int key = t & 63, ds0 = (t >> 6) * 32;
      const float* src = pv + (nrow + k0 + key) * DP + ds0;
#pragma unroll
      for (int e = 0; e < 32; e += 4) {
        float4 a = *(const float4*)(src + e);
        int dv = ds0 + e;
        *(unsigned short*)((char*)Vs + (((dv + 0) * 128 + key * 2) ^ (((dv + 0) & 7) << 4))) = f2bf(a.x);
        *(unsigned short*)((char*)Vs + (((dv + 1) * 128 + key * 2) ^ (((dv + 1) & 7) << 4))) = f2bf(a.y);
        *(unsigned short*)((char*)Vs + (((dv + 2) * 128 + key * 2) ^ (((dv + 2) & 7) << 4))) = f2bf(a.z);
        *(unsigned short*)((char*)Vs + (((dv + 3) * 128 + key * 2) ^ (((dv + 3) & 7) << 4))) = f2bf(a.w);
      }
    }
    __syncthreads();
    // QK^T
    f32x4 sacc[4];
#pragma unroll
    for (int cs = 0; cs < 4; cs++) sacc[cs] = (f32x4){0.f, 0.f, 0.f, 0.f};
#pragma unroll
    for (int ks = 0; ks < 4; ks++) {
#pragma unroll
      for (int cs = 0; cs < 4; cs++) {
        int key = cs * 16 + lo;
        int byte = (key * 256 + (ks * 32 + hi * 8) * 2) ^ ((key & 7) << 4);
        bf16x8 bk = *(const bf16x8*)((char*)Ks + byte);
        sacc[cs] = __builtin_amdgcn_mfma_f32_16x16x32_bf16(qf[ks], bk, sacc[cs], 0, 0, 0);
      }
    }
    // online softmax (no bias, no clamp)
#pragma unroll
    for (int i = 0; i < 4; i++) {
      float mrow = fmaxf(fmaxf(sacc[0][i], sacc[1][i]), fmaxf(sacc[2][i], sacc[3][i]));
#pragma unroll
      for (int ofs = 1; ofs < 16; ofs <<= 1) mrow = fmaxf(mrow, __shfl_xor(mrow, ofs, 64));
      float mn = fmaxf(m_s[i], mrow);
      float scale = __expf(m_s[i] - mn);
      float ts = 0.f;
      int r = hi * 4 + i;
#pragma unroll
      for (int cs = 0; cs < 4; cs++) {
        float p = __expf(sacc[cs][i] - mn);
        ts += p;
        int key = cs * 16 + lo;
        int byte = (r * 128 + key * 2) ^ ((r & 7) << 4);
        *(unsigned short*)(PsW + byte) = f2bf(p);
      }
#pragma unroll
      for (int ofs = 1; ofs < 16; ofs <<= 1) ts += __shfl_xor(ts, ofs, 64);
      l_s[i] = l_s[i] * scale + ts;
      m_s[i] = mn;
#pragma unroll
      for (int vc = 0; vc < 8; vc++) o_acc[vc][i] *= scale;
    }
    // PV
#pragma unroll
    for (int ks2 = 0; ks2 < 2; ks2++) {
      int byte = (lo * 128 + (ks2 * 32 + hi * 8) * 2) ^ ((lo & 7) << 4);
      bf16x8 pa = *(const bf16x8*)(PsW + byte);
#pragma unroll
      for (int vc = 0; vc < 8; vc++) {
        int dv = vc * 16 + lo;
        int vbyte = (dv * 128 + (ks2 * 32 + hi * 8) * 2) ^ ((dv & 7) << 4);
        bf16x8 bv = *(const bf16x8*)((char*)Vs + vbyte);
        o_acc[vc] = __builtin_amdgcn_mfma_f32_16x16x32_bf16(pa, bv, o_acc[vc], 0, 0, 0);
      }
    }
    __syncthreads();
  }
  // epilogue: /l + residual
#pragma unroll
  for (int i = 0; i < 4; i++) {
    float inv = 1.0f / l_s[i];
    size_t grow = ((size_t)(nbase + nl) * NP + i0 + w * 16 + hi * 4 + i) * DP;
#pragma unroll
    for (int vc = 0; vc < 8; vc++) {
      int dv = vc * 16 + lo;
      out[grow + dv] = o_acc[vc][i] * inv + resid[grow + dv];
    }
  }
}

// fused pairwise FF, 8 rows per block
__global__ __launch_bounds__(256) void pw_ff_kernel(const float* __restrict__ X,
                                                    const float* __restrict__ wp,
                                                    const float* __restrict__ w1,
                                                    const float* __restrict__ b1,
                                                    const float* __restrict__ w2,
                                                    const float* __restrict__ b2,
                                                    float* __restrict__ out) {
  __shared__ __align__(16) float xs[8][128];
  __shared__ __align__(16) float hs[8][256];
  int b = blockIdx.x, t = threadIdx.x;
  size_t row0 = (size_t)b * 8;
  int r = t >> 5, l = t & 31;
  const float* xr = X + (row0 + r) * DP;
  float v[4];
  float ss = 0.f;
#pragma unroll
  for (int e = 0; e < 4; e++) { v[e] = xr[l + 32 * e]; ss += v[e] * v[e]; }
#pragma unroll
  for (int o = 16; o > 0; o >>= 1) ss += __shfl_xor(ss, o, 64);
  float rs = rsqrtf(ss * (1.0f / 128.0f) + EPS_RMS);
#pragma unroll
  for (int e = 0; e < 4; e++) xs[r][l + 32 * e] = v[e] * rs * wp[l + 32 * e];
  __syncthreads();
  {
    float acc[8];
    float bb = b1[t];
#pragma unroll
    for (int rr = 0; rr < 8; rr++) acc[rr] = bb;
    for (int d = 0; d < 128; d += 4) {
      float w0 = w1[(size_t)(d + 0) * DPI + t];
      float w1v = w1[(size_t)(d + 1) * DPI + t];
      float w2v = w1[(size_t)(d + 2) * DPI + t];
      float w3 = w1[(size_t)(d + 3) * DPI + t];
#pragma unroll
      for (int rr = 0; rr < 8; rr++) {
        float4 xv = *(const float4*)&xs[rr][d];
        acc[rr] += xv.x * w0 + xv.y * w1v + xv.z * w2v + xv.w * w3;
      }
    }
#pragma unroll
    for (int rr = 0; rr < 8; rr++) hs[rr][t] = fmaxf(acc[rr], 0.f);
  }
  __syncthreads();
  int c = t & 127, g = t >> 7;
  float ob[4];
  float bb2 = b2[c];
#pragma unroll
  for (int rr = 0; rr < 4; rr++) ob[rr] = bb2;
  for (int tt = 0; tt < 256; tt += 4) {
    float w0 = w2[(size_t)(tt + 0) * DP + c];
    float w1v = w2[(size_t)(tt + 1) * DP + c];
    float w2v = w2[(size_t)(tt + 2) * DP + c];
    float w3 = w2[(size_t)(tt + 3) * DP + c];
#pragma unroll
    for (int rr = 0; rr < 4; rr++) {
      float4 hv = *(const float4*)&hs[g * 4 + rr][tt];
      ob[rr] += hv.x * w0 + hv.y * w1v + hv.z * w2v + hv.w * w3;
    }
  }
#pragma unroll
  for (int rr = 0; rr < 4; rr++) {
    size_t gi = (row0 + g * 4 + rr) * DP + c;
    out[gi] = ob[rr] + X[gi];
  }
}

__global__ void out_kernel(const float* __restrict__ S, const float* __restrict__ P,
                           float* __restrict__ out) {
  size_t idx = (size_t)blockIdx.x * 256 + threadIdx.x;
  const size_t n1 = (size_t)SEQ * DMODEL;
  const size_t n2 = (size_t)NPR * DP;
  if (idx < n1) out[idx] = S[idx];
  else if (idx < n1 + n2) out[idx] = P[idx - n1];
}

extern "C" void kernel_launch(void* const* d_in, const int* in_sizes, int n_in,
                              void* d_out, int out_size, void* d_ws, size_t ws_size,
                              hipStream_t stream) {
  const float* in_single   = (const float*)d_in[0];
  const float* in_pair     = (const float*)d_in[1];
  const float* attn_pre_w  = (const float*)d_in[2];
  const float* attn_post_w = (const float*)d_in[3];
  const float* qkv_w       = (const float*)d_in[4];
  const float* q_norm_w    = (const float*)d_in[5];
  const float* k_norm_w    = (const float*)d_in[6];
  const float* v_norm_w    = (const float*)d_in[7];
  const float* bias_rms_w  = (const float*)d_in[8];
  const float* bias_proj_w = (const float*)d_in[9];
  const float* out_w       = (const float*)d_in[10];
  const float* ff_pre_w    = (const float*)d_in[11];
  const float* ff_post_w   = (const float*)d_in[12];
  const float* ff_w1       = (const float*)d_in[13];
  const float* ff_b1       = (const float*)d_in[14];
  const float* ff_w2       = (const float*)d_in[15];
  const float* ff_b2       = (const float*)d_in[16];
  const float* pw_attn_pre = (const float*)d_in[17];
  const float* pw_qk_w     = (const float*)d_in[18];
  const float* pw_v_w      = (const float*)d_in[19];
  const float* pw_v_b      = (const float*)d_in[20];
  const float* pw_ff_pre   = (const float*)d_in[21];
  const float* pw_ff_w1    = (const float*)d_in[22];
  const float* pw_ff_b1    = (const float*)d_in[23];
  const float* pw_ff_w2    = (const float*)d_in[24];
  const float* pw_ff_b2    = (const float*)d_in[25];

  float* ws = (float*)d_ws;
  float* S    = ws;                  // 1,572,864
  float* Pc   = ws + 1572864;        // 8,388,608
  float* Pa   = ws + 9961472;        // 8,388,608
  float* pbt  = ws + 18350080;       // 524,288  [h][row]
  float* pos  = ws + 18874368;       // 262,144
  float* scP  = ws + 19136512;       // 65,536
  float* scS  = ws + 19202048;       // 2,048
  float* TMP  = ws + 19204096;       // 8,650,752 (union)
  // single-track overlays:
  float* qkv  = TMP;                 // 2,752,512
  float* q_r  = TMP + 2752512;       // 2,097,152
  float* k_n  = TMP + 4849664;       // 262,144 (row-major [seq][128])
  float* v_t  = TMP + 5111808;       // 393,216 (transposed [192][seq])
  float* ao   = TMP + 5505024;       // 3,145,728
  unsigned short* WtA = (unsigned short*)(TMP + 5505024);  // qkv weights bf16 (pre-attn, ao dead)
  unsigned short* WtX = (unsigned short*)(TMP);            // out/ff weights bf16 (qkv dead)
  float* t2   = TMP + 655360;        // 1,572,864
  float* t1   = TMP + 2752512;       // 3,145,728
  // pairwise overlays:
  float* pqkc = TMP;                 // 4,194,304 ([16384, 256])
  float* pvc  = TMP + 4194304;       // 2,097,152 ([16384, 128])
  unsigned short* WtE = (unsigned short*)(TMP + 6400000);  // pw_qk^T bf16
  unsigned short* WtF = (unsigned short*)(TMP + 6420000);  // pw_v^T bf16

  hipMemcpyAsync(S, in_single, 1572864 * sizeof(float), hipMemcpyDeviceToDevice, stream);
  hipMemcpyAsync(Pc, in_pair, (size_t)8388608 * sizeof(float), hipMemcpyDeviceToDevice, stream);
  pos_kernel<<<SEQ, 64, 0, stream>>>(pos);

  for (int i = 0; i < 4; i++) {
    int j = i / 2;
    rowscale_kernel<<<NPR, 64, 0, stream>>>(Pc, scP, DP);
    rowscale_kernel<<<SEQ, 64, 0, stream>>>(S, scS, DMODEL);
    pb_kernel<<<2048, 256, 0, stream>>>(Pc, scP, bias_rms_w + i * DP,
                                        bias_proj_w + (size_t)i * DP * 8, pbt);
    // qkv = rmsnorm(S) @ qkv_w   [bf16 MFMA]
    convT_kernel<<<dim3(QKVN / 32, DMODEL / 32), 256, 0, stream>>>(
        qkv_w + (size_t)i * DMODEL * QKVN, WtA, DMODEL, QKVN);
    gemm_bf16<<<dim3(11, 16), 256, 0, stream>>>(S, WtA, qkv, SEQ, QKVN, DMODEL,
                                                nullptr, nullptr, 0, scS, attn_pre_w + i * DMODEL);
    qk_prep_kernel<<<dim3(SEQ, 9), 64, 0, stream>>>(qkv, q_norm_w + i * DQK, k_norm_w + i * DQK,
                                                    pos, q_r, k_n);
    v_prep_kernel<<<SEQ, 64, 0, stream>>>(qkv, v_norm_w + i * DV, v_t);
    attn_mfma<<<dim3(SEQ / 64, NHEAD), 256, 0, stream>>>(q_r, k_n, v_t, pbt, ao);
    // t2 = ao @ out_w
    convT_kernel<<<dim3(DMODEL / 32, (NHEAD * DV) / 32), 256, 0, stream>>>(
        out_w + (size_t)i * (NHEAD * DV) * DMODEL, WtX, NHEAD * DV, DMODEL);
    gemm_bf16<<<dim3(6, 16), 256, 0, stream>>>(ao, WtX, t2, SEQ, DMODEL, NHEAD * DV,
                                               nullptr, nullptr, 0, nullptr, nullptr);
    rmsres_kernel<<<SEQ, 64, 0, stream>>>(t2, attn_post_w + i * DMODEL, S, S, DMODEL);
    // feedforward
    rowscale_kernel<<<SEQ, 64, 0, stream>>>(S, scS, DMODEL);
    convT_kernel<<<dim3(FFI / 32, DMODEL / 32), 256, 0, stream>>>(
        ff_w1 + (size_t)i * DMODEL * FFI, WtX, DMODEL, FFI);
    gemm_bf16<<<dim3(12, 16), 256, 0, stream>>>(S, WtX, t1, SEQ, FFI, DMODEL,
                                                ff_b1 + i * FFI, nullptr, 1, scS, ff_pre_w + i * DMODEL);
    convT_kernel<<<dim3(DMODEL / 32, FFI / 32), 256, 0, stream>>>(
        ff_w2 + (size_t)i * FFI * DMODEL, WtX, FFI, DMODEL);
    gemm_bf16<<<dim3(6, 16), 256, 0, stream>>>(t1, WtX, t2, SEQ, DMODEL, FFI,
                                               ff_b2 + i * DMODEL, nullptr, 0, nullptr, nullptr);
    rmsres_kernel<<<SEQ, 64, 0, stream>>>(t2, ff_post_w + i * DMODEL, S, S, DMODEL);
    // pairwise track (layers 0, 2), chunked over n in 4 x 64 rows
    if ((i & 1) == 0) {
      convT_kernel<<<dim3((2 * DP) / 32, DP / 32), 256, 0, stream>>>(
          pw_qk_w + (size_t)j * DP * 2 * DP, WtE, DP, 2 * DP);
      convT_kernel<<<dim3(DP / 32, DP / 32), 256, 0, stream>>>(
          pw_v_w + (size_t)j * DP * DP, WtF, DP, DP);
      for (int c = 0; c < 4; c++) {
        const float* Ac = Pc + (size_t)c * 16384 * DP;
        const float* sc = scP + c * 16384;
        gemm_bf16<<<dim3(2, 128), 256, 0, stream>>>(Ac, WtE, pqkc, 16384, 2 * DP, DP,
                                                    nullptr, nullptr, 0, sc, pw_attn_pre + j * DP);
        gemm_bf16<<<dim3(1, 128), 256, 0, stream>>>(Ac, WtF, pvc, 16384, DP, DP,
                                                    pw_v_b + j * DP, nullptr, 0, sc, pw_attn_pre + j * DP);
        pw_attn_mfma<<<dim3(4, 64), 256, 0, stream>>>(pqkc, pvc, Pc, Pa, c * 64);
      }
      pw_ff_kernel<<<NPR / 8, 256, 0, stream>>>(Pa, pw_ff_pre + j * DP,
                                                pw_ff_w1 + (size_t)j * DP * DPI, pw_ff_b1 + j * DPI,
                                                pw_ff_w2 + (size_t)j * DPI * DP, pw_ff_b2 + j * DP, Pc);
    }
  }
  size_t total = (size_t)SEQ * DMODEL + (size_t)NPR * DP;
  out_kernel<<<(total + 255) / 256, 256, 0, stream>>>(S, Pc, (float*)d_out);
}